// Round 4
// baseline (2684.840 us; speedup 1.0000x reference)
//
#include <hip/hip_runtime.h>
#include <hip/hip_bf16.h>

typedef __hip_bfloat16 bf16;
typedef __attribute__((ext_vector_type(8))) short short8v;
typedef __attribute__((ext_vector_type(4))) float float4v;

#define N_TOK (4 * 65536)
#define IMG 256

__device__ __forceinline__ float wave_reduce_add(float v) {
#pragma unroll
  for (int m = 32; m > 0; m >>= 1) v += __shfl_xor(v, m, 64);
  return v;
}

__device__ __forceinline__ float gelu_f(float v) {
  return 0.5f * v * (1.f + erff(v * 0.70710678118654752f));
}

// fragment-linear activation layout: [t=row/64][ch=k/8][r=row%64][j=k%8]
__device__ __forceinline__ size_t frag_idx(long row, int k) {
  return ((((row >> 6) * 24) + (k >> 3)) << 9) + ((long)(row & 63) << 3) + (k & 7);
}

// ---------------- small utility / pack kernels ----------------

__global__ void k_zero(float* __restrict__ p, int n) {
  int i = blockIdx.x * 256 + threadIdx.x;
  if (i < n) p[i] = 0.f;
}

// qkv B pack: [nt 34][kb 6][lane 64][8], n-order: oo = h*90 + (mat*30 + d), q pre-scaled
__global__ void k_pack_qkv_b(const float* __restrict__ w, bf16* __restrict__ B) {
  int e = blockIdx.x * 256 + threadIdx.x;
  if (e >= 34 * 6 * 64) return;
  int lane = e & 63, kb = (e >> 6) % 6, nt = e / (6 * 64);
  int n = nt * 16 + (lane & 15);
  int kbase = kb * 32 + (lane >> 4) * 8;
  bf16* out = B + (size_t)e * 8;
#pragma unroll
  for (int j = 0; j < 8; j++) {
    int k = kbase + j;
    float v = 0.f;
    if (n < 540 && k < 180) {
      int hh = n / 90, r = n % 90, mat = r / 30, d = r % 30;
      int o = mat * 180 + hh * 30 + d;
      float s = (mat == 0) ? 0.18257418583505537f : 1.f;
      v = w[o * 180 + k] * s;
    }
    out[j] = __float2bfloat16(v);
  }
}

__global__ void k_pack_qkv_bias(const float* __restrict__ b, float* __restrict__ bt) {
  int n = blockIdx.x * 256 + threadIdx.x;
  if (n >= 544) return;
  float v = 0.f;
  if (n < 540) {
    int hh = n / 90, r = n % 90, mat = r / 30, d = r % 30;
    int o = mat * 180 + hh * 30 + d;
    float s = (mat == 0) ? 0.18257418583505537f : 1.f;
    v = b[o] * s;
  }
  bt[n] = v;
}

// proj B pack: [nt 12][kb 6][lane][8]: B[k][n] = proj_w[n*180+k]
__global__ void k_pack_proj_b(const float* __restrict__ w, bf16* __restrict__ B) {
  int e = blockIdx.x * 256 + threadIdx.x;
  if (e >= 12 * 6 * 64) return;
  int lane = e & 63, kb = (e >> 6) % 6, nt = e / (6 * 64);
  int n = nt * 16 + (lane & 15);
  int kbase = kb * 32 + (lane >> 4) * 8;
  bf16* out = B + (size_t)e * 8;
#pragma unroll
  for (int j = 0; j < 8; j++) {
    int k = kbase + j;
    out[j] = __float2bfloat16((n < 180 && k < 180) ? w[n * 180 + k] : 0.f);
  }
}

// fc1 B pack: [nt 46][kb 6][lane][8]: B[k][n] = fc1_w[n*180+k]
__global__ void k_pack_fc1_b(const float* __restrict__ w, bf16* __restrict__ B) {
  int e = blockIdx.x * 256 + threadIdx.x;
  if (e >= 46 * 6 * 64) return;
  int lane = e & 63, kb = (e >> 6) % 6, nt = e / (6 * 64);
  int n = nt * 16 + (lane & 15);
  int kbase = kb * 32 + (lane >> 4) * 8;
  bf16* out = B + (size_t)e * 8;
#pragma unroll
  for (int j = 0; j < 8; j++) {
    int k = kbase + j;
    out[j] = __float2bfloat16((n < 720 && k < 180) ? w[n * 180 + k] : 0.f);
  }
}

__global__ void k_pack_fc1_bias(const float* __restrict__ b, float* __restrict__ bt) {
  int n = blockIdx.x * 256 + threadIdx.x;
  if (n >= 736) return;
  bt[n] = (n < 720) ? b[n] : 0.f;
}

// fc2 B pack: [nt 12][kb 23][lane][8]: B[k][n] = fc2_w[n*720+k]
__global__ void k_pack_fc2_b(const float* __restrict__ w, bf16* __restrict__ B) {
  int e = blockIdx.x * 256 + threadIdx.x;
  if (e >= 12 * 23 * 64) return;
  int lane = e & 63, kb = (e >> 6) % 23, nt = e / (23 * 64);
  int n = nt * 16 + (lane & 15);
  int kbase = kb * 32 + (lane >> 4) * 8;
  bf16* out = B + (size_t)e * 8;
#pragma unroll
  for (int j = 0; j < 8; j++) {
    int k = kbase + j;
    out[j] = __float2bfloat16((n < 180 && k < 720) ? w[n * 720 + k] : 0.f);
  }
}

// conv1 B pack: frag = ((dy*6+kb)*3+dx)*4+nt ; B[k][n] = w1[n][k][dy][dx]
// n = out-ch (60 pad 64), k = in-ch (180 pad 192)
__global__ void k_pack_conv1_b(const float* __restrict__ w, bf16* __restrict__ B) {
  int e = blockIdx.x * 256 + threadIdx.x;
  if (e >= 9 * 6 * 4 * 64) return;
  int lane = e & 63;
  int t = e >> 6;
  int nt = t & 3;
  int t2 = t >> 2;
  int dx = t2 % 3;
  int t3 = t2 / 3;
  int kb = t3 % 6, dy = t3 / 6;
  int n = nt * 16 + (lane & 15);
  int kbase = kb * 32 + (lane >> 4) * 8;
  bf16* out = B + (size_t)e * 8;
#pragma unroll
  for (int j = 0; j < 8; j++) {
    int k = kbase + j;
    float v = (n < 60 && k < 180) ? w[((n * 180 + k) * 3 + dy) * 3 + dx] : 0.f;
    out[j] = __float2bfloat16(v);
  }
}

// conv2 B pack: frag = ((dy*2+kb)*3+dx)*12+nt ; B[k][n] = w2[n][k][dy][dx]
// n = out-ch (180 pad 192), k = in-ch (60 pad 64)
__global__ void k_pack_conv2_b(const float* __restrict__ w, bf16* __restrict__ B) {
  int e = blockIdx.x * 256 + threadIdx.x;
  if (e >= 9 * 2 * 12 * 64) return;
  int lane = e & 63;
  int t = e >> 6;
  int nt = t % 12;
  int t2 = t / 12;
  int dx = t2 % 3;
  int t3 = t2 / 3;
  int kb = t3 & 1, dy = t3 >> 1;
  int n = nt * 16 + (lane & 15);
  int kbase = kb * 32 + (lane >> 4) * 8;
  bf16* out = B + (size_t)e * 8;
#pragma unroll
  for (int j = 0; j < 8; j++) {
    int k = kbase + j;
    float v = (n < 180 && k < 60) ? w[((n * 60 + k) * 3 + dy) * 3 + dx] : 0.f;
    out[j] = __float2bfloat16(v);
  }
}

// ---------------- LN1: x -> xn (frag layout, K padded to 192 w/ zeros) ----------------

__global__ __launch_bounds__(256) void k_ln1(const float* __restrict__ x,
                                             const float* __restrict__ gw,
                                             const float* __restrict__ bw,
                                             bf16* __restrict__ xnf) {
  int wv = threadIdx.x >> 6, lane = threadIdx.x & 63;
  long row = (long)blockIdx.x * 4 + wv;
  const float* xr = x + row * 180;
  float v0 = xr[lane];
  float v1 = xr[lane + 64];
  float v2 = (lane < 52) ? xr[lane + 128] : 0.f;
  float s = wave_reduce_add(v0 + v1 + v2);
  float ss = wave_reduce_add(v0 * v0 + v1 * v1 + v2 * v2);
  float mean = s * (1.f / 180.f);
  float rstd = rsqrtf(ss * (1.f / 180.f) - mean * mean + 1e-5f);
  bf16* base = xnf + (((row >> 6) * 24) << 9) + ((long)(row & 63) << 3);
  int ch = lane >> 3, j = lane & 7;
  base[((size_t)ch << 9) + j] =
      __float2bfloat16((v0 - mean) * rstd * gw[lane] + bw[lane]);
  base[((size_t)(ch + 8) << 9) + j] =
      __float2bfloat16((v1 - mean) * rstd * gw[lane + 64] + bw[lane + 64]);
  float v3 = (lane < 52) ? ((v2 - mean) * rstd * gw[lane + 128] + bw[lane + 128]) : 0.f;
  base[((size_t)(ch + 16) << 9) + j] = __float2bfloat16(v3);
}

// ---------------- conv1 3x3 180->60 + GELU via MFMA ----------------
// block = 64 output pixels of one image row. Two K-halves (96 ch each) staged
// in LDS: Ls[r(3)][chb_l(12)][px(66)][8]. Wave = M-tile (16 px), loops nt.

__global__ __launch_bounds__(256) void k_conv1_mfma(const bf16* __restrict__ xnf,
                                                    const bf16* __restrict__ Bc1,
                                                    const float* __restrict__ b1,
                                                    bf16* __restrict__ y60f) {
  __shared__ bf16 Ls[3 * 12 * 66 * 8];  // 38016 B
  int tid = threadIdx.x;
  int bid = blockIdx.x;
  int b = bid >> 10, rem = bid & 1023, iy = rem >> 2, xb = rem & 3;
  int ix0 = xb << 6;
  long ibase = (long)b * 65536;
  int lane = tid & 63, wv = tid >> 6;
  int m = lane & 15, q = lane >> 4;
  float4v acc[4];
#pragma unroll
  for (int nt = 0; nt < 4; nt++) acc[nt] = (float4v){0.f, 0.f, 0.f, 0.f};
  const short8v* Bp = (const short8v*)Bc1;
  for (int half = 0; half < 2; half++) {
    for (int idx = tid; idx < 3 * 12 * 66; idx += 256) {
      int px = idx % 66;
      int t2 = idx / 66;
      int chb = t2 % 12, r = t2 / 12;
      int iy2 = iy - 1 + r, ix = ix0 - 1 + px;
      uint4 v = make_uint4(0u, 0u, 0u, 0u);
      if (iy2 >= 0 && iy2 < IMG && ix >= 0 && ix < IMG) {
        long tok = ibase + iy2 * IMG + ix;
        v = *(const uint4*)(xnf + ((tok >> 6) * 24 + half * 12 + chb) * 512 +
                            (tok & 63) * 8);
      }
      *(uint4*)(Ls + (size_t)idx * 8) = v;
    }
    __syncthreads();
#pragma unroll
    for (int kbl = 0; kbl < 3; kbl++) {
      int kb = half * 3 + kbl;
#pragma unroll
      for (int dy = 0; dy < 3; dy++) {
        const short8v* ab =
            (const short8v*)Ls + ((dy * 12 + kbl * 4 + q) * 66 + wv * 16 + m);
#pragma unroll
        for (int dx = 0; dx < 3; dx++) {
          short8v a = ab[dx];
          const short8v* bp = Bp + (size_t)(((dy * 6 + kb) * 3 + dx) * 4) * 64 + lane;
#pragma unroll
          for (int nt = 0; nt < 4; nt++)
            acc[nt] = __builtin_amdgcn_mfma_f32_16x16x32_bf16(a, bp[nt * 64], acc[nt], 0, 0, 0);
        }
      }
    }
    __syncthreads();
  }
  // epilogue: GELU + store frag layout [tb][chb 8][p 64][8]; zero pad ch 60..63
  bf16* outb = y60f + (size_t)bid * 4096;
#pragma unroll
  for (int nt = 0; nt < 4; nt++) {
    int n = nt * 16 + m;
    float bias = (n < 60) ? b1[n] : 0.f;
#pragma unroll
    for (int reg = 0; reg < 4; reg++) {
      int p = wv * 16 + q * 4 + reg;
      float v = (n < 60) ? gelu_f(acc[nt][reg] + bias) : 0.f;
      outb[((n >> 3) << 9) + (p << 3) + (n & 7)] = __float2bfloat16(v);
    }
  }
}

// ---------------- conv2 3x3 60->180 via MFMA + fused channel sums ----------------
// Ls[r(3)][chb(8)][px(66)][8] = 25344 B. Wave = M-tile, 12 N-tiles.

__global__ __launch_bounds__(256) void k_conv2_mfma(const bf16* __restrict__ y60f,
                                                    const bf16* __restrict__ Bc2,
                                                    const float* __restrict__ b2,
                                                    bf16* __restrict__ y180f,
                                                    float* __restrict__ chsum) {
  __shared__ bf16 Ls[3 * 8 * 66 * 8];  // 25344 B
  int tid = threadIdx.x;
  int bid = blockIdx.x;
  int b = bid >> 10, rem = bid & 1023, iy = rem >> 2, xb = rem & 3;
  int ix0 = xb << 6;
  long ibase = (long)b * 65536;
  for (int idx = tid; idx < 3 * 8 * 66; idx += 256) {
    int px = idx % 66;
    int t2 = idx / 66;
    int chb = t2 % 8, r = t2 / 8;
    int iy2 = iy - 1 + r, ix = ix0 - 1 + px;
    uint4 v = make_uint4(0u, 0u, 0u, 0u);
    if (iy2 >= 0 && iy2 < IMG && ix >= 0 && ix < IMG) {
      long tok = ibase + iy2 * IMG + ix;
      v = *(const uint4*)(y60f + ((tok >> 6) * 8 + chb) * 512 + (tok & 63) * 8);
    }
    *(uint4*)(Ls + (size_t)idx * 8) = v;
  }
  __syncthreads();
  int lane = tid & 63, wv = tid >> 6;
  int m = lane & 15, q = lane >> 4;
  float4v acc[12];
#pragma unroll
  for (int nt = 0; nt < 12; nt++) acc[nt] = (float4v){0.f, 0.f, 0.f, 0.f};
  const short8v* Bp = (const short8v*)Bc2;
#pragma unroll
  for (int dy = 0; dy < 3; dy++) {
#pragma unroll
    for (int kb = 0; kb < 2; kb++) {
      const short8v* ab =
          (const short8v*)Ls + ((dy * 8 + kb * 4 + q) * 66 + wv * 16 + m);
#pragma unroll
      for (int dx = 0; dx < 3; dx++) {
        short8v a = ab[dx];
        const short8v* bp = Bp + (size_t)(((dy * 2 + kb) * 3 + dx) * 12) * 64 + lane;
#pragma unroll
        for (int nt = 0; nt < 12; nt++)
          acc[nt] = __builtin_amdgcn_mfma_f32_16x16x32_bf16(a, bp[nt * 64], acc[nt], 0, 0, 0);
      }
    }
  }
  // epilogue: bias + store frag layout + per-channel partial sums
  float csum[12];
  bf16* outb = y180f + (size_t)bid * 12288;
#pragma unroll
  for (int nt = 0; nt < 12; nt++) {
    int n = nt * 16 + m;
    float bias = (n < 180) ? b2[n] : 0.f;
    float s = 0.f;
#pragma unroll
    for (int reg = 0; reg < 4; reg++) {
      float v = acc[nt][reg] + bias;
      s += v;
      int p = wv * 16 + q * 4 + reg;
      if (n < 180) outb[((n >> 3) << 9) + (p << 3) + (n & 7)] = __float2bfloat16(v);
    }
    s += __shfl_xor(s, 16, 64);
    s += __shfl_xor(s, 32, 64);
    csum[nt] = s;
  }
  __syncthreads();  // Ls reads done in all waves; reuse as fp32 scratch
  float* red = (float*)Ls;  // [4][192]
  if (q == 0) {
#pragma unroll
    for (int nt = 0; nt < 12; nt++) red[wv * 192 + nt * 16 + m] = csum[nt];
  }
  __syncthreads();
  if (tid < 180) {
    float tot = red[tid] + red[192 + tid] + red[384 + tid] + red[576 + tid];
    atomicAdd(&chsum[b * 180 + tid], tot);
  }
}

// ---------------- SE ----------------

__global__ __launch_bounds__(192) void k_se(const float* __restrict__ cs,
                                            const float* __restrict__ w1,
                                            const float* __restrict__ b1,
                                            const float* __restrict__ w2,
                                            const float* __restrict__ b2,
                                            float* __restrict__ a_se) {
  __shared__ float m[180];
  __shared__ float hid[6];
  int b = blockIdx.x, t = threadIdx.x;
  if (t < 180) m[t] = cs[b * 180 + t] * (1.f / 65536.f);
  __syncthreads();
  if (t < 6) {
    float s = b1[t];
    for (int c = 0; c < 180; c++) s += m[c] * w1[t * 180 + c];
    hid[t] = fmaxf(s, 0.f);
  }
  __syncthreads();
  if (t < 180) {
    float s = b2[t];
#pragma unroll
    for (int j = 0; j < 6; j++) s += hid[j] * w2[t * 6 + j];
    a_se[b * 180 + t] = 1.f / (1.f + __expf(-s));
  }
}

// ---------------- qkv GEMM via MFMA: 64 rows/block, N=544, K=192 ----------------

__global__ __launch_bounds__(256) void k_qkv_mfma(const bf16* __restrict__ xnf,
                                                  const bf16* __restrict__ Bq,
                                                  const float* __restrict__ btq,
                                                  bf16* __restrict__ qkvb) {
  __shared__ bf16 As[24 * 64 * 8];  // 24 KB, frag-linear
  int tid = threadIdx.x;
  const uint4* src = (const uint4*)(xnf + (size_t)blockIdx.x * 12288);
  uint4* dst = (uint4*)As;
#pragma unroll
  for (int it = 0; it < 6; it++) dst[it * 256 + tid] = src[it * 256 + tid];
  __syncthreads();
  int lane = tid & 63, wv = tid >> 6;
  int m = lane & 15, q = lane >> 4;
  long row0 = (long)blockIdx.x * 64 + wv * 16;
  const short8v* Ap = (const short8v*)As;
  const short8v* Bp = (const short8v*)Bq;
  for (int nt = 0; nt < 34; nt += 2) {
    float4v acc0 = {0.f, 0.f, 0.f, 0.f}, acc1 = {0.f, 0.f, 0.f, 0.f};
#pragma unroll
    for (int kb = 0; kb < 6; kb++) {
      short8v a = Ap[(kb * 4 + q) * 64 + wv * 16 + m];
      short8v b0 = Bp[(nt * 6 + kb) * 64 + lane];
      short8v b1 = Bp[((nt + 1) * 6 + kb) * 64 + lane];
      acc0 = __builtin_amdgcn_mfma_f32_16x16x32_bf16(a, b0, acc0, 0, 0, 0);
      acc1 = __builtin_amdgcn_mfma_f32_16x16x32_bf16(a, b1, acc1, 0, 0, 0);
    }
    int n0 = nt * 16 + m, n1 = n0 + 16;
    float bb0 = btq[n0], bb1 = btq[n1];
#pragma unroll
    for (int reg = 0; reg < 4; reg++) {
      long rw = row0 + q * 4 + reg;
      qkvb[rw * 544 + n0] = __float2bfloat16(acc0[reg] + bb0);
      qkvb[rw * 544 + n1] = __float2bfloat16(acc1[reg] + bb1);
    }
  }
}

// ---------------- attention per (window, head); writes frag layout ----------------

__global__ __launch_bounds__(256) void k_attn(const bf16* __restrict__ qkvb,
                                              const float* __restrict__ btab,
                                              const int* __restrict__ rpi,
                                              bf16* __restrict__ attnf) {
  __shared__ float qkvh[90 * 65];
  __shared__ float sT[64 * 65];
  int h = blockIdx.y;
  int bid = blockIdx.x;
  int b = bid >> 10, rem = bid & 1023, wi = rem >> 5, wj = rem & 31;
  long ibase = (long)b * 65536;
  // zero k-pad (180..191) once per token, by head-0 blocks
  if (h == 0 && threadIdx.x < 64) {
    int n = threadIdx.x;
    long g = ibase + (wi * 8 + (n >> 3)) * IMG + wj * 8 + (n & 7);
    bf16* bp = attnf + (((g >> 6) * 24) << 9) + ((long)(g & 63) << 3);
    *(uint2*)(bp + (22 << 9) + 4) = make_uint2(0u, 0u);
    *(uint4*)(bp + (23 << 9)) = make_uint4(0u, 0u, 0u, 0u);
  }
  for (int idx = threadIdx.x; idx < 64 * 90; idx += 256) {
    int t = idx / 90, r = idx % 90;
    long g = ibase + (wi * 8 + (t >> 3)) * IMG + wj * 8 + (t & 7);
    qkvh[r * 65 + t] = __bfloat162float(qkvb[g * 544 + h * 90 + r]);
  }
  __syncthreads();
  {
    int m = threadIdx.x & 63, ng = threadIdx.x >> 6;
    int n0 = ng * 16;
    float acc[16];
#pragma unroll
    for (int j = 0; j < 16; j++) acc[j] = 0.f;
    for (int d = 0; d < 30; d++) {
      float kv = qkvh[(30 + d) * 65 + m];
      const float* qp = qkvh + d * 65 + n0;
#pragma unroll
      for (int j = 0; j < 16; j++) acc[j] += kv * qp[j];
    }
#pragma unroll
    for (int j = 0; j < 16; j++) {
      int n = n0 + j;
      sT[m * 65 + n] = acc[j] + btab[rpi[n * 64 + m] * 6 + h];
    }
  }
  __syncthreads();
  if (threadIdx.x < 64) {
    int n = threadIdx.x;
    float mx = -1e30f;
    for (int m2 = 0; m2 < 64; m2++) mx = fmaxf(mx, sT[m2 * 65 + n]);
    float s = 0.f;
    for (int m2 = 0; m2 < 64; m2++) {
      float e = __expf(sT[m2 * 65 + n] - mx);
      sT[m2 * 65 + n] = e;
      s += e;
    }
    float inv = 1.f / s;
    for (int m2 = 0; m2 < 64; m2++) sT[m2 * 65 + n] *= inv;
  }
  __syncthreads();
  for (int it = threadIdx.x; it < 120; it += 256) {
    int d = it % 30, ng = it / 30;
    int n0 = ng * 16;
    float acc[16];
#pragma unroll
    for (int j = 0; j < 16; j++) acc[j] = 0.f;
    for (int m2 = 0; m2 < 64; m2++) {
      float vv = qkvh[(60 + d) * 65 + m2];
      const float* pp = sT + m2 * 65 + n0;
#pragma unroll
      for (int j = 0; j < 16; j++) acc[j] += vv * pp[j];
    }
    int k = h * 30 + d;
#pragma unroll
    for (int j = 0; j < 16; j++) {
      int n = n0 + j;
      long g = ibase + (wi * 8 + (n >> 3)) * IMG + wj * 8 + (n & 7);
      attnf[frag_idx(g, k)] = __float2bfloat16(acc[j]);
    }
  }
}

// ---------------- proj via MFMA + residual combine -> out (fp32) ----------------

__global__ __launch_bounds__(256) void k_proj_mfma(const bf16* __restrict__ attnf,
                                                   const bf16* __restrict__ Bp_,
                                                   const float* __restrict__ pb,
                                                   const float* __restrict__ x0,
                                                   const bf16* __restrict__ y180f,
                                                   const float* __restrict__ a_se,
                                                   float* __restrict__ out) {
  __shared__ bf16 As[24 * 64 * 8];
  int tid = threadIdx.x;
  const uint4* src = (const uint4*)(attnf + (size_t)blockIdx.x * 12288);
  uint4* dst = (uint4*)As;
#pragma unroll
  for (int it = 0; it < 6; it++) dst[it * 256 + tid] = src[it * 256 + tid];
  __syncthreads();
  int lane = tid & 63, wv = tid >> 6;
  int m = lane & 15, q = lane >> 4;
  long row0 = (long)blockIdx.x * 64 + wv * 16;
  const short8v* Ap = (const short8v*)As;
  const short8v* Bpp = (const short8v*)Bp_;
  for (int nt = 0; nt < 12; nt += 2) {
    float4v acc0 = {0.f, 0.f, 0.f, 0.f}, acc1 = {0.f, 0.f, 0.f, 0.f};
#pragma unroll
    for (int kb = 0; kb < 6; kb++) {
      short8v a = Ap[(kb * 4 + q) * 64 + wv * 16 + m];
      short8v b0 = Bpp[(nt * 6 + kb) * 64 + lane];
      short8v b1 = Bpp[((nt + 1) * 6 + kb) * 64 + lane];
      acc0 = __builtin_amdgcn_mfma_f32_16x16x32_bf16(a, b0, acc0, 0, 0, 0);
      acc1 = __builtin_amdgcn_mfma_f32_16x16x32_bf16(a, b1, acc1, 0, 0, 0);
    }
    int n0 = nt * 16 + m, n1 = n0 + 16;
    float pb0 = pb[n0];
    float pb1 = (n1 < 180) ? pb[n1] : 0.f;
#pragma unroll
    for (int reg = 0; reg < 4; reg++) {
      long rw = row0 + q * 4 + reg;
      int bidx = (int)(rw >> 16);
      long gi0 = rw * 180 + n0;
      out[gi0] = x0[gi0] + acc0[reg] + pb0 +
                 __bfloat162float(y180f[frag_idx(rw, n0)]) * a_se[bidx * 180 + n0] * 0.01f;
      if (n1 < 180) {
        long gi1 = rw * 180 + n1;
        out[gi1] = x0[gi1] + acc1[reg] + pb1 +
                   __bfloat162float(y180f[frag_idx(rw, n1)]) * a_se[bidx * 180 + n1] * 0.01f;
      }
    }
  }
}

// ---------------- fused LN2 + FC1(GELU) + FC2 + residual, all MFMA ----------------

__global__ __launch_bounds__(256) void k_mlp_mfma(float* __restrict__ xio,
                                                  const float* __restrict__ gw,
                                                  const float* __restrict__ bw,
                                                  const bf16* __restrict__ B1,
                                                  const float* __restrict__ b1t,
                                                  const bf16* __restrict__ B2,
                                                  const float* __restrict__ fc2b) {
  __shared__ bf16 Axs[32 * 200];  // LN'd rows, row-major, stride 200
  __shared__ bf16 Hs[32 * 744];   // hidden, row-major, stride 744
  int tid = threadIdx.x, lane = tid & 63, wv = tid >> 6;
  long row0 = (long)blockIdx.x * 32;
  // LN2
  for (int rr = 0; rr < 8; rr++) {
    int r = wv * 8 + rr;
    const float* xr = xio + (row0 + r) * 180;
    float v0 = xr[lane], v1 = xr[lane + 64];
    float v2 = (lane < 52) ? xr[lane + 128] : 0.f;
    float s = wave_reduce_add(v0 + v1 + v2);
    float ss = wave_reduce_add(v0 * v0 + v1 * v1 + v2 * v2);
    float mean = s * (1.f / 180.f);
    float rstd = rsqrtf(ss * (1.f / 180.f) - mean * mean + 1e-5f);
    bf16* ar = Axs + r * 200;
    ar[lane] = __float2bfloat16((v0 - mean) * rstd * gw[lane] + bw[lane]);
    ar[lane + 64] = __float2bfloat16((v1 - mean) * rstd * gw[lane + 64] + bw[lane + 64]);
    float v3 = (lane < 52) ? ((v2 - mean) * rstd * gw[lane + 128] + bw[lane + 128]) : 0.f;
    ar[lane + 128] = __float2bfloat16(v3);
  }
  __syncthreads();
  int m = lane & 15, q = lane >> 4, mh = wv & 1, ng = wv >> 1;
  int rA = mh * 16 + m;
  // FC1 + GELU -> Hs
  for (int i = 0; i < 23; i += 2) {
    int nt0 = ng * 23 + i;
    bool two = (i + 1) < 23;
    float4v acc0 = {0.f, 0.f, 0.f, 0.f}, acc1 = {0.f, 0.f, 0.f, 0.f};
#pragma unroll
    for (int kb = 0; kb < 6; kb++) {
      short8v a = *(const short8v*)(Axs + rA * 200 + kb * 32 + q * 8);
      short8v b0 = ((const short8v*)B1)[(nt0 * 6 + kb) * 64 + lane];
      acc0 = __builtin_amdgcn_mfma_f32_16x16x32_bf16(a, b0, acc0, 0, 0, 0);
      if (two) {
        short8v b1 = ((const short8v*)B1)[((nt0 + 1) * 6 + kb) * 64 + lane];
        acc1 = __builtin_amdgcn_mfma_f32_16x16x32_bf16(a, b1, acc1, 0, 0, 0);
      }
    }
    int n0 = nt0 * 16 + m;
    float bb0 = b1t[n0];
    float bb1 = two ? b1t[n0 + 16] : 0.f;
#pragma unroll
    for (int reg = 0; reg < 4; reg++) {
      int r = mh * 16 + q * 4 + reg;
      Hs[r * 744 + n0] = __float2bfloat16(gelu_f(acc0[reg] + bb0));
      if (two) Hs[r * 744 + n0 + 16] = __float2bfloat16(gelu_f(acc1[reg] + bb1));
    }
  }
  __syncthreads();
  // FC2 + residual
  for (int i = 0; i < 6; i += 2) {
    int nt0 = ng * 6 + i;
    float4v acc0 = {0.f, 0.f, 0.f, 0.f}, acc1 = {0.f, 0.f, 0.f, 0.f};
    for (int kb = 0; kb < 23; kb++) {
      short8v a = *(const short8v*)(Hs + rA * 744 + kb * 32 + q * 8);
      short8v b0 = ((const short8v*)B2)[(nt0 * 23 + kb) * 64 + lane];
      short8v b1 = ((const short8v*)B2)[((nt0 + 1) * 23 + kb) * 64 + lane];
      acc0 = __builtin_amdgcn_mfma_f32_16x16x32_bf16(a, b0, acc0, 0, 0, 0);
      acc1 = __builtin_amdgcn_mfma_f32_16x16x32_bf16(a, b1, acc1, 0, 0, 0);
    }
    int n0 = nt0 * 16 + m, n1 = n0 + 16;
#pragma unroll
    for (int reg = 0; reg < 4; reg++) {
      long rw = row0 + mh * 16 + q * 4 + reg;
      if (n0 < 180) xio[rw * 180 + n0] += acc0[reg] + fc2b[n0];
      if (n1 < 180) xio[rw * 180 + n1] += acc1[reg] + fc2b[n1];
    }
  }
}

// ---------------- launch ----------------

extern "C" void kernel_launch(void* const* d_in, const int* in_sizes, int n_in,
                              void* d_out, int out_size, void* d_ws, size_t ws_size,
                              hipStream_t stream) {
  const float* x = (const float*)d_in[0];
  const float* ln1g = (const float*)d_in[1];
  const float* ln1b = (const float*)d_in[2];
  const float* qkvw = (const float*)d_in[3];
  const float* qkvbias = (const float*)d_in[4];
  const float* btab = (const float*)d_in[5];
  const float* projw = (const float*)d_in[6];
  const float* projb = (const float*)d_in[7];
  const float* cw1 = (const float*)d_in[8];
  const float* cb1 = (const float*)d_in[9];
  const float* cw2 = (const float*)d_in[10];
  const float* cb2 = (const float*)d_in[11];
  const float* caw1 = (const float*)d_in[12];
  const float* cab1 = (const float*)d_in[13];
  const float* caw2 = (const float*)d_in[14];
  const float* cab2 = (const float*)d_in[15];
  const float* ln2g = (const float*)d_in[16];
  const float* ln2b = (const float*)d_in[17];
  const float* fc1w = (const float*)d_in[18];
  const float* fc1b = (const float*)d_in[19];
  const float* fc2w = (const float*)d_in[20];
  const float* fc2b = (const float*)d_in[21];
  const int* rpi = (const int*)d_in[22];
  float* out = (float*)d_out;

  size_t off = 0;
  char* wsb = (char*)d_ws;
  auto alloc = [&](size_t bytes) -> char* {
    char* p = wsb + off;
    off = (off + bytes + 255) & ~(size_t)255;
    return p;
  };
  bf16* xnf = (bf16*)alloc((size_t)N_TOK * 192 * 2);   // also reused as attnf
  bf16* y60f = (bf16*)alloc((size_t)N_TOK * 64 * 2);
  bf16* y180f = (bf16*)alloc((size_t)N_TOK * 192 * 2);
  bf16* qkvb = (bf16*)alloc((size_t)N_TOK * 544 * 2);
  bf16* Bq = (bf16*)alloc(34 * 6 * 64 * 8 * 2);
  float* btq = (float*)alloc(544 * 4);
  bf16* Bp = (bf16*)alloc(12 * 6 * 64 * 8 * 2);
  bf16* B1 = (bf16*)alloc(46 * 6 * 64 * 8 * 2);
  float* b1t = (float*)alloc(736 * 4);
  bf16* B2 = (bf16*)alloc(12 * 23 * 64 * 8 * 2);
  bf16* Bc1 = (bf16*)alloc(9 * 6 * 4 * 64 * 8 * 2);
  bf16* Bc2 = (bf16*)alloc(9 * 2 * 12 * 64 * 8 * 2);
  float* chsum = (float*)alloc(720 * 4);
  float* a_se = (float*)alloc(720 * 4);
  if (off > ws_size) return;
  bf16* attnf = xnf;  // xnf dead after k_qkv/k_conv1; reuse for attention output

  k_zero<<<3, 256, 0, stream>>>(chsum, 720);
  k_pack_qkv_b<<<51, 256, 0, stream>>>(qkvw, Bq);
  k_pack_qkv_bias<<<3, 256, 0, stream>>>(qkvbias, btq);
  k_pack_proj_b<<<18, 256, 0, stream>>>(projw, Bp);
  k_pack_fc1_b<<<69, 256, 0, stream>>>(fc1w, B1);
  k_pack_fc1_bias<<<3, 256, 0, stream>>>(fc1b, b1t);
  k_pack_fc2_b<<<69, 256, 0, stream>>>(fc2w, B2);
  k_pack_conv1_b<<<54, 256, 0, stream>>>(cw1, Bc1);
  k_pack_conv2_b<<<54, 256, 0, stream>>>(cw2, Bc2);

  k_ln1<<<65536, 256, 0, stream>>>(x, ln1g, ln1b, xnf);
  k_conv1_mfma<<<4096, 256, 0, stream>>>(xnf, Bc1, cb1, y60f);
  k_conv2_mfma<<<4096, 256, 0, stream>>>(y60f, Bc2, cb2, y180f, chsum);
  k_se<<<4, 192, 0, stream>>>(chsum, caw1, cab1, caw2, cab2, a_se);
  k_qkv_mfma<<<4096, 256, 0, stream>>>(xnf, Bq, btq, qkvb);
  k_attn<<<dim3(4096, 6), 256, 0, stream>>>(qkvb, btab, rpi, attnf);
  k_proj_mfma<<<4096, 256, 0, stream>>>(attnf, Bp, projb, x, y180f, a_se, out);
  k_mlp_mfma<<<8192, 256, 0, stream>>>(out, ln2g, ln2b, B1, b1t, B2, fc2b);
}

// Round 5
// 2320.255 us; speedup vs baseline: 1.1571x; 1.1571x over previous
//
#include <hip/hip_runtime.h>
#include <hip/hip_bf16.h>

typedef __hip_bfloat16 bf16;
typedef __attribute__((ext_vector_type(8))) short short8v;
typedef __attribute__((ext_vector_type(4))) float float4v;

#define N_TOK (4 * 65536)
#define IMG 256

__device__ __forceinline__ float wave_reduce_add(float v) {
#pragma unroll
  for (int m = 32; m > 0; m >>= 1) v += __shfl_xor(v, m, 64);
  return v;
}

__device__ __forceinline__ float gelu_f(float v) {
  return 0.5f * v * (1.f + erff(v * 0.70710678118654752f));
}

// fragment-linear activation layout: [t=row/64][ch=k/8][r=row%64][j=k%8]
__device__ __forceinline__ size_t frag_idx(long row, int k) {
  return ((((row >> 6) * 24) + (k >> 3)) << 9) + ((long)(row & 63) << 3) + (k & 7);
}

// ---------------- small utility / pack kernels ----------------

__global__ void k_zero(float* __restrict__ p, int n) {
  int i = blockIdx.x * 256 + threadIdx.x;
  if (i < n) p[i] = 0.f;
}

// qkv B pack: [nt 34][kb 6][lane 64][8], n-order: oo = h*90 + (mat*30 + d), q pre-scaled
__global__ void k_pack_qkv_b(const float* __restrict__ w, bf16* __restrict__ B) {
  int e = blockIdx.x * 256 + threadIdx.x;
  if (e >= 34 * 6 * 64) return;
  int lane = e & 63, kb = (e >> 6) % 6, nt = e / (6 * 64);
  int n = nt * 16 + (lane & 15);
  int kbase = kb * 32 + (lane >> 4) * 8;
  bf16* out = B + (size_t)e * 8;
#pragma unroll
  for (int j = 0; j < 8; j++) {
    int k = kbase + j;
    float v = 0.f;
    if (n < 540 && k < 180) {
      int hh = n / 90, r = n % 90, mat = r / 30, d = r % 30;
      int o = mat * 180 + hh * 30 + d;
      float s = (mat == 0) ? 0.18257418583505537f : 1.f;
      v = w[o * 180 + k] * s;
    }
    out[j] = __float2bfloat16(v);
  }
}

__global__ void k_pack_qkv_bias(const float* __restrict__ b, float* __restrict__ bt) {
  int n = blockIdx.x * 256 + threadIdx.x;
  if (n >= 544) return;
  float v = 0.f;
  if (n < 540) {
    int hh = n / 90, r = n % 90, mat = r / 30, d = r % 30;
    int o = mat * 180 + hh * 30 + d;
    float s = (mat == 0) ? 0.18257418583505537f : 1.f;
    v = b[o] * s;
  }
  bt[n] = v;
}

// proj B pack: [nt 12][kb 6][lane][8]: B[k][n] = proj_w[n*180+k]
__global__ void k_pack_proj_b(const float* __restrict__ w, bf16* __restrict__ B) {
  int e = blockIdx.x * 256 + threadIdx.x;
  if (e >= 12 * 6 * 64) return;
  int lane = e & 63, kb = (e >> 6) % 6, nt = e / (6 * 64);
  int n = nt * 16 + (lane & 15);
  int kbase = kb * 32 + (lane >> 4) * 8;
  bf16* out = B + (size_t)e * 8;
#pragma unroll
  for (int j = 0; j < 8; j++) {
    int k = kbase + j;
    out[j] = __float2bfloat16((n < 180 && k < 180) ? w[n * 180 + k] : 0.f);
  }
}

// fc1 B pack: [nt 46][kb 6][lane][8]: B[k][n] = fc1_w[n*180+k]
__global__ void k_pack_fc1_b(const float* __restrict__ w, bf16* __restrict__ B) {
  int e = blockIdx.x * 256 + threadIdx.x;
  if (e >= 46 * 6 * 64) return;
  int lane = e & 63, kb = (e >> 6) % 6, nt = e / (6 * 64);
  int n = nt * 16 + (lane & 15);
  int kbase = kb * 32 + (lane >> 4) * 8;
  bf16* out = B + (size_t)e * 8;
#pragma unroll
  for (int j = 0; j < 8; j++) {
    int k = kbase + j;
    out[j] = __float2bfloat16((n < 720 && k < 180) ? w[n * 180 + k] : 0.f);
  }
}

__global__ void k_pack_fc1_bias(const float* __restrict__ b, float* __restrict__ bt) {
  int n = blockIdx.x * 256 + threadIdx.x;
  if (n >= 736) return;
  bt[n] = (n < 720) ? b[n] : 0.f;
}

// fc2 B pack: [nt 12][kb 23][lane][8]: B[k][n] = fc2_w[n*720+k]
__global__ void k_pack_fc2_b(const float* __restrict__ w, bf16* __restrict__ B) {
  int e = blockIdx.x * 256 + threadIdx.x;
  if (e >= 12 * 23 * 64) return;
  int lane = e & 63, kb = (e >> 6) % 23, nt = e / (23 * 64);
  int n = nt * 16 + (lane & 15);
  int kbase = kb * 32 + (lane >> 4) * 8;
  bf16* out = B + (size_t)e * 8;
#pragma unroll
  for (int j = 0; j < 8; j++) {
    int k = kbase + j;
    out[j] = __float2bfloat16((n < 180 && k < 720) ? w[n * 720 + k] : 0.f);
  }
}

// conv1 B pack: frag = ((dy*6+kb)*3+dx)*4+nt ; B[k][n] = w1[n][k][dy][dx]
// n = out-ch (60 pad 64), k = in-ch (180 pad 192)
__global__ void k_pack_conv1_b(const float* __restrict__ w, bf16* __restrict__ B) {
  int e = blockIdx.x * 256 + threadIdx.x;
  if (e >= 9 * 6 * 4 * 64) return;
  int lane = e & 63;
  int t = e >> 6;
  int nt = t & 3;
  int t2 = t >> 2;
  int dx = t2 % 3;
  int t3 = t2 / 3;
  int kb = t3 % 6, dy = t3 / 6;
  int n = nt * 16 + (lane & 15);
  int kbase = kb * 32 + (lane >> 4) * 8;
  bf16* out = B + (size_t)e * 8;
#pragma unroll
  for (int j = 0; j < 8; j++) {
    int k = kbase + j;
    float v = (n < 60 && k < 180) ? w[((n * 180 + k) * 3 + dy) * 3 + dx] : 0.f;
    out[j] = __float2bfloat16(v);
  }
}

// conv2 B pack: frag = ((dy*2+kb)*3+dx)*12+nt ; B[k][n] = w2[n][k][dy][dx]
// n = out-ch (180 pad 192), k = in-ch (60 pad 64)
__global__ void k_pack_conv2_b(const float* __restrict__ w, bf16* __restrict__ B) {
  int e = blockIdx.x * 256 + threadIdx.x;
  if (e >= 9 * 2 * 12 * 64) return;
  int lane = e & 63;
  int t = e >> 6;
  int nt = t % 12;
  int t2 = t / 12;
  int dx = t2 % 3;
  int t3 = t2 / 3;
  int kb = t3 & 1, dy = t3 >> 1;
  int n = nt * 16 + (lane & 15);
  int kbase = kb * 32 + (lane >> 4) * 8;
  bf16* out = B + (size_t)e * 8;
#pragma unroll
  for (int j = 0; j < 8; j++) {
    int k = kbase + j;
    float v = (n < 180 && k < 60) ? w[((n * 60 + k) * 3 + dy) * 3 + dx] : 0.f;
    out[j] = __float2bfloat16(v);
  }
}

// ---------------- LN1: x -> xn (frag layout, K padded to 192 w/ zeros) ----------------

__global__ __launch_bounds__(256) void k_ln1(const float* __restrict__ x,
                                             const float* __restrict__ gw,
                                             const float* __restrict__ bw,
                                             bf16* __restrict__ xnf) {
  int wv = threadIdx.x >> 6, lane = threadIdx.x & 63;
  long row = (long)blockIdx.x * 4 + wv;
  const float* xr = x + row * 180;
  float v0 = xr[lane];
  float v1 = xr[lane + 64];
  float v2 = (lane < 52) ? xr[lane + 128] : 0.f;
  float s = wave_reduce_add(v0 + v1 + v2);
  float ss = wave_reduce_add(v0 * v0 + v1 * v1 + v2 * v2);
  float mean = s * (1.f / 180.f);
  float rstd = rsqrtf(ss * (1.f / 180.f) - mean * mean + 1e-5f);
  bf16* base = xnf + (((row >> 6) * 24) << 9) + ((long)(row & 63) << 3);
  int ch = lane >> 3, j = lane & 7;
  base[((size_t)ch << 9) + j] =
      __float2bfloat16((v0 - mean) * rstd * gw[lane] + bw[lane]);
  base[((size_t)(ch + 8) << 9) + j] =
      __float2bfloat16((v1 - mean) * rstd * gw[lane + 64] + bw[lane + 64]);
  float v3 = (lane < 52) ? ((v2 - mean) * rstd * gw[lane + 128] + bw[lane + 128]) : 0.f;
  base[((size_t)(ch + 16) << 9) + j] = __float2bfloat16(v3);
}

// ---------------- conv1 3x3 180->60 + GELU via MFMA ----------------
// block = 64 output pixels of one image row. Two K-halves (96 ch each) staged
// in LDS: Ls[r(3)][chb_l(12)][px(66)][8]. Wave = M-tile (16 px), loops nt.

__global__ __launch_bounds__(256) void k_conv1_mfma(const bf16* __restrict__ xnf,
                                                    const bf16* __restrict__ Bc1,
                                                    const float* __restrict__ b1,
                                                    bf16* __restrict__ y60f) {
  __shared__ bf16 Ls[3 * 12 * 66 * 8];  // 38016 B
  int tid = threadIdx.x;
  int bid = blockIdx.x;
  int b = bid >> 10, rem = bid & 1023, iy = rem >> 2, xb = rem & 3;
  int ix0 = xb << 6;
  long ibase = (long)b * 65536;
  int lane = tid & 63, wv = tid >> 6;
  int m = lane & 15, q = lane >> 4;
  float4v acc[4];
#pragma unroll
  for (int nt = 0; nt < 4; nt++) acc[nt] = (float4v){0.f, 0.f, 0.f, 0.f};
  const short8v* Bp = (const short8v*)Bc1;
  for (int half = 0; half < 2; half++) {
    for (int idx = tid; idx < 3 * 12 * 66; idx += 256) {
      int px = idx % 66;
      int t2 = idx / 66;
      int chb = t2 % 12, r = t2 / 12;
      int iy2 = iy - 1 + r, ix = ix0 - 1 + px;
      uint4 v = make_uint4(0u, 0u, 0u, 0u);
      if (iy2 >= 0 && iy2 < IMG && ix >= 0 && ix < IMG) {
        long tok = ibase + iy2 * IMG + ix;
        v = *(const uint4*)(xnf + ((tok >> 6) * 24 + half * 12 + chb) * 512 +
                            (tok & 63) * 8);
      }
      *(uint4*)(Ls + (size_t)idx * 8) = v;
    }
    __syncthreads();
#pragma unroll
    for (int kbl = 0; kbl < 3; kbl++) {
      int kb = half * 3 + kbl;
#pragma unroll
      for (int dy = 0; dy < 3; dy++) {
        const short8v* ab =
            (const short8v*)Ls + ((dy * 12 + kbl * 4 + q) * 66 + wv * 16 + m);
#pragma unroll
        for (int dx = 0; dx < 3; dx++) {
          short8v a = ab[dx];
          const short8v* bp = Bp + (size_t)(((dy * 6 + kb) * 3 + dx) * 4) * 64 + lane;
#pragma unroll
          for (int nt = 0; nt < 4; nt++)
            acc[nt] = __builtin_amdgcn_mfma_f32_16x16x32_bf16(a, bp[nt * 64], acc[nt], 0, 0, 0);
        }
      }
    }
    __syncthreads();
  }
  // epilogue: GELU + store frag layout [tb][chb 8][p 64][8]; zero pad ch 60..63
  bf16* outb = y60f + (size_t)bid * 4096;
#pragma unroll
  for (int nt = 0; nt < 4; nt++) {
    int n = nt * 16 + m;
    float bias = (n < 60) ? b1[n] : 0.f;
#pragma unroll
    for (int reg = 0; reg < 4; reg++) {
      int p = wv * 16 + q * 4 + reg;
      float v = (n < 60) ? gelu_f(acc[nt][reg] + bias) : 0.f;
      outb[((n >> 3) << 9) + (p << 3) + (n & 7)] = __float2bfloat16(v);
    }
  }
}

// ---------------- conv2 3x3 60->180 via MFMA + fused channel sums ----------------
// Ls[r(3)][chb(8)][px(66)][8] = 25344 B. Wave = M-tile, 12 N-tiles.

__global__ __launch_bounds__(256) void k_conv2_mfma(const bf16* __restrict__ y60f,
                                                    const bf16* __restrict__ Bc2,
                                                    const float* __restrict__ b2,
                                                    bf16* __restrict__ y180f,
                                                    float* __restrict__ chsum) {
  __shared__ bf16 Ls[3 * 8 * 66 * 8];  // 25344 B
  int tid = threadIdx.x;
  int bid = blockIdx.x;
  int b = bid >> 10, rem = bid & 1023, iy = rem >> 2, xb = rem & 3;
  int ix0 = xb << 6;
  long ibase = (long)b * 65536;
  for (int idx = tid; idx < 3 * 8 * 66; idx += 256) {
    int px = idx % 66;
    int t2 = idx / 66;
    int chb = t2 % 8, r = t2 / 8;
    int iy2 = iy - 1 + r, ix = ix0 - 1 + px;
    uint4 v = make_uint4(0u, 0u, 0u, 0u);
    if (iy2 >= 0 && iy2 < IMG && ix >= 0 && ix < IMG) {
      long tok = ibase + iy2 * IMG + ix;
      v = *(const uint4*)(y60f + ((tok >> 6) * 8 + chb) * 512 + (tok & 63) * 8);
    }
    *(uint4*)(Ls + (size_t)idx * 8) = v;
  }
  __syncthreads();
  int lane = tid & 63, wv = tid >> 6;
  int m = lane & 15, q = lane >> 4;
  float4v acc[12];
#pragma unroll
  for (int nt = 0; nt < 12; nt++) acc[nt] = (float4v){0.f, 0.f, 0.f, 0.f};
  const short8v* Bp = (const short8v*)Bc2;
#pragma unroll
  for (int dy = 0; dy < 3; dy++) {
#pragma unroll
    for (int kb = 0; kb < 2; kb++) {
      const short8v* ab =
          (const short8v*)Ls + ((dy * 8 + kb * 4 + q) * 66 + wv * 16 + m);
#pragma unroll
      for (int dx = 0; dx < 3; dx++) {
        short8v a = ab[dx];
        const short8v* bp = Bp + (size_t)(((dy * 2 + kb) * 3 + dx) * 12) * 64 + lane;
#pragma unroll
        for (int nt = 0; nt < 12; nt++)
          acc[nt] = __builtin_amdgcn_mfma_f32_16x16x32_bf16(a, bp[nt * 64], acc[nt], 0, 0, 0);
      }
    }
  }
  // epilogue: bias + store frag layout + per-channel partial sums
  float csum[12];
  bf16* outb = y180f + (size_t)bid * 12288;
#pragma unroll
  for (int nt = 0; nt < 12; nt++) {
    int n = nt * 16 + m;
    float bias = (n < 180) ? b2[n] : 0.f;
    float s = 0.f;
#pragma unroll
    for (int reg = 0; reg < 4; reg++) {
      float v = acc[nt][reg] + bias;
      s += v;
      int p = wv * 16 + q * 4 + reg;
      if (n < 180) outb[((n >> 3) << 9) + (p << 3) + (n & 7)] = __float2bfloat16(v);
    }
    s += __shfl_xor(s, 16, 64);
    s += __shfl_xor(s, 32, 64);
    csum[nt] = s;
  }
  __syncthreads();  // Ls reads done in all waves; reuse as fp32 scratch
  float* red = (float*)Ls;  // [4][192]
  if (q == 0) {
#pragma unroll
    for (int nt = 0; nt < 12; nt++) red[wv * 192 + nt * 16 + m] = csum[nt];
  }
  __syncthreads();
  if (tid < 180) {
    float tot = red[tid] + red[192 + tid] + red[384 + tid] + red[576 + tid];
    atomicAdd(&chsum[b * 180 + tid], tot);
  }
}

// ---------------- SE ----------------

__global__ __launch_bounds__(192) void k_se(const float* __restrict__ cs,
                                            const float* __restrict__ w1,
                                            const float* __restrict__ b1,
                                            const float* __restrict__ w2,
                                            const float* __restrict__ b2,
                                            float* __restrict__ a_se) {
  __shared__ float m[180];
  __shared__ float hid[6];
  int b = blockIdx.x, t = threadIdx.x;
  if (t < 180) m[t] = cs[b * 180 + t] * (1.f / 65536.f);
  __syncthreads();
  if (t < 6) {
    float s = b1[t];
    for (int c = 0; c < 180; c++) s += m[c] * w1[t * 180 + c];
    hid[t] = fmaxf(s, 0.f);
  }
  __syncthreads();
  if (t < 180) {
    float s = b2[t];
#pragma unroll
    for (int j = 0; j < 6; j++) s += hid[j] * w2[t * 6 + j];
    a_se[b * 180 + t] = 1.f / (1.f + __expf(-s));
  }
}

// ---------------- qkv GEMM via MFMA: 64 rows/block, N=544, K=192 ----------------

__global__ __launch_bounds__(256) void k_qkv_mfma(const bf16* __restrict__ xnf,
                                                  const bf16* __restrict__ Bq,
                                                  const float* __restrict__ btq,
                                                  bf16* __restrict__ qkvb) {
  __shared__ bf16 As[24 * 64 * 8];  // 24 KB, frag-linear
  int tid = threadIdx.x;
  const uint4* src = (const uint4*)(xnf + (size_t)blockIdx.x * 12288);
  uint4* dst = (uint4*)As;
#pragma unroll
  for (int it = 0; it < 6; it++) dst[it * 256 + tid] = src[it * 256 + tid];
  __syncthreads();
  int lane = tid & 63, wv = tid >> 6;
  int m = lane & 15, q = lane >> 4;
  long row0 = (long)blockIdx.x * 64 + wv * 16;
  const short8v* Ap = (const short8v*)As;
  const short8v* Bp = (const short8v*)Bq;
  for (int nt = 0; nt < 34; nt += 2) {
    float4v acc0 = {0.f, 0.f, 0.f, 0.f}, acc1 = {0.f, 0.f, 0.f, 0.f};
#pragma unroll
    for (int kb = 0; kb < 6; kb++) {
      short8v a = Ap[(kb * 4 + q) * 64 + wv * 16 + m];
      short8v b0 = Bp[(nt * 6 + kb) * 64 + lane];
      short8v b1 = Bp[((nt + 1) * 6 + kb) * 64 + lane];
      acc0 = __builtin_amdgcn_mfma_f32_16x16x32_bf16(a, b0, acc0, 0, 0, 0);
      acc1 = __builtin_amdgcn_mfma_f32_16x16x32_bf16(a, b1, acc1, 0, 0, 0);
    }
    int n0 = nt * 16 + m, n1 = n0 + 16;
    float bb0 = btq[n0], bb1 = btq[n1];
#pragma unroll
    for (int reg = 0; reg < 4; reg++) {
      long rw = row0 + q * 4 + reg;
      qkvb[rw * 544 + n0] = __float2bfloat16(acc0[reg] + bb0);
      qkvb[rw * 544 + n1] = __float2bfloat16(acc1[reg] + bb1);
    }
  }
}

// ---------------- attention per (window, head); writes frag layout ----------------

__global__ __launch_bounds__(256) void k_attn(const bf16* __restrict__ qkvb,
                                              const float* __restrict__ btab,
                                              const int* __restrict__ rpi,
                                              bf16* __restrict__ attnf) {
  __shared__ float qkvh[90 * 65];
  __shared__ float sT[64 * 65];
  int h = blockIdx.y;
  int bid = blockIdx.x;
  int b = bid >> 10, rem = bid & 1023, wi = rem >> 5, wj = rem & 31;
  long ibase = (long)b * 65536;
  // zero k-pad (180..191) once per token, by head-0 blocks
  if (h == 0 && threadIdx.x < 64) {
    int n = threadIdx.x;
    long g = ibase + (wi * 8 + (n >> 3)) * IMG + wj * 8 + (n & 7);
    bf16* bp = attnf + (((g >> 6) * 24) << 9) + ((long)(g & 63) << 3);
    *(uint2*)(bp + (22 << 9) + 4) = make_uint2(0u, 0u);
    *(uint4*)(bp + (23 << 9)) = make_uint4(0u, 0u, 0u, 0u);
  }
  for (int idx = threadIdx.x; idx < 64 * 90; idx += 256) {
    int t = idx / 90, r = idx % 90;
    long g = ibase + (wi * 8 + (t >> 3)) * IMG + wj * 8 + (t & 7);
    qkvh[r * 65 + t] = __bfloat162float(qkvb[g * 544 + h * 90 + r]);
  }
  __syncthreads();
  {
    int m = threadIdx.x & 63, ng = threadIdx.x >> 6;
    int n0 = ng * 16;
    float acc[16];
#pragma unroll
    for (int j = 0; j < 16; j++) acc[j] = 0.f;
    for (int d = 0; d < 30; d++) {
      float kv = qkvh[(30 + d) * 65 + m];
      const float* qp = qkvh + d * 65 + n0;
#pragma unroll
      for (int j = 0; j < 16; j++) acc[j] += kv * qp[j];
    }
#pragma unroll
    for (int j = 0; j < 16; j++) {
      int n = n0 + j;
      sT[m * 65 + n] = acc[j] + btab[rpi[n * 64 + m] * 6 + h];
    }
  }
  __syncthreads();
  if (threadIdx.x < 64) {
    int n = threadIdx.x;
    float mx = -1e30f;
    for (int m2 = 0; m2 < 64; m2++) mx = fmaxf(mx, sT[m2 * 65 + n]);
    float s = 0.f;
    for (int m2 = 0; m2 < 64; m2++) {
      float e = __expf(sT[m2 * 65 + n] - mx);
      sT[m2 * 65 + n] = e;
      s += e;
    }
    float inv = 1.f / s;
    for (int m2 = 0; m2 < 64; m2++) sT[m2 * 65 + n] *= inv;
  }
  __syncthreads();
  for (int it = threadIdx.x; it < 120; it += 256) {
    int d = it % 30, ng = it / 30;
    int n0 = ng * 16;
    float acc[16];
#pragma unroll
    for (int j = 0; j < 16; j++) acc[j] = 0.f;
    for (int m2 = 0; m2 < 64; m2++) {
      float vv = qkvh[(60 + d) * 65 + m2];
      const float* pp = sT + m2 * 65 + n0;
#pragma unroll
      for (int j = 0; j < 16; j++) acc[j] += vv * pp[j];
    }
    int k = h * 30 + d;
#pragma unroll
    for (int j = 0; j < 16; j++) {
      int n = n0 + j;
      long g = ibase + (wi * 8 + (n >> 3)) * IMG + wj * 8 + (n & 7);
      attnf[frag_idx(g, k)] = __float2bfloat16(acc[j]);
    }
  }
}

// ---------------- proj via MFMA + residual combine -> out (fp32) ----------------

__global__ __launch_bounds__(256) void k_proj_mfma(const bf16* __restrict__ attnf,
                                                   const bf16* __restrict__ Bp_,
                                                   const float* __restrict__ pb,
                                                   const float* __restrict__ x0,
                                                   const bf16* __restrict__ y180f,
                                                   const float* __restrict__ a_se,
                                                   float* __restrict__ out) {
  __shared__ bf16 As[24 * 64 * 8];
  int tid = threadIdx.x;
  const uint4* src = (const uint4*)(attnf + (size_t)blockIdx.x * 12288);
  uint4* dst = (uint4*)As;
#pragma unroll
  for (int it = 0; it < 6; it++) dst[it * 256 + tid] = src[it * 256 + tid];
  __syncthreads();
  int lane = tid & 63, wv = tid >> 6;
  int m = lane & 15, q = lane >> 4;
  long row0 = (long)blockIdx.x * 64 + wv * 16;
  const short8v* Ap = (const short8v*)As;
  const short8v* Bpp = (const short8v*)Bp_;
  for (int nt = 0; nt < 12; nt += 2) {
    float4v acc0 = {0.f, 0.f, 0.f, 0.f}, acc1 = {0.f, 0.f, 0.f, 0.f};
#pragma unroll
    for (int kb = 0; kb < 6; kb++) {
      short8v a = Ap[(kb * 4 + q) * 64 + wv * 16 + m];
      short8v b0 = Bpp[(nt * 6 + kb) * 64 + lane];
      short8v b1 = Bpp[((nt + 1) * 6 + kb) * 64 + lane];
      acc0 = __builtin_amdgcn_mfma_f32_16x16x32_bf16(a, b0, acc0, 0, 0, 0);
      acc1 = __builtin_amdgcn_mfma_f32_16x16x32_bf16(a, b1, acc1, 0, 0, 0);
    }
    int n0 = nt * 16 + m, n1 = n0 + 16;
    float pb0 = pb[n0];
    float pb1 = (n1 < 180) ? pb[n1] : 0.f;
#pragma unroll
    for (int reg = 0; reg < 4; reg++) {
      long rw = row0 + q * 4 + reg;
      int bidx = (int)(rw >> 16);
      long gi0 = rw * 180 + n0;
      out[gi0] = x0[gi0] + acc0[reg] + pb0 +
                 __bfloat162float(y180f[frag_idx(rw, n0)]) * a_se[bidx * 180 + n0] * 0.01f;
      if (n1 < 180) {
        long gi1 = rw * 180 + n1;
        out[gi1] = x0[gi1] + acc1[reg] + pb1 +
                   __bfloat162float(y180f[frag_idx(rw, n1)]) * a_se[bidx * 180 + n1] * 0.01f;
      }
    }
  }
}

// ---------------- fused LN2 + FC1(GELU) + FC2 + residual, all MFMA ----------------
// 512 threads / 8 waves, 32 rows per block. Same LDS (60.4 KB -> 2 blocks/CU)
// but 16 waves/CU (50% occupancy) instead of 8: halves per-wave MFMA chain,
// doubles latency hiding. B L2 traffic per block unchanged.

__global__ __launch_bounds__(512, 4) void k_mlp_mfma(float* __restrict__ xio,
                                                     const float* __restrict__ gw,
                                                     const float* __restrict__ bw,
                                                     const bf16* __restrict__ B1,
                                                     const float* __restrict__ b1t,
                                                     const bf16* __restrict__ B2,
                                                     const float* __restrict__ fc2b) {
  __shared__ bf16 Axs[32 * 200];  // LN'd rows, row-major, stride 200
  __shared__ bf16 Hs[32 * 744];   // hidden, row-major, stride 744
  int tid = threadIdx.x, lane = tid & 63, wv = tid >> 6;  // wv 0..7
  long row0 = (long)blockIdx.x * 32;
  // LN2: each wave handles 4 rows
#pragma unroll
  for (int rr = 0; rr < 4; rr++) {
    int r = wv * 4 + rr;
    const float* xr = xio + (row0 + r) * 180;
    float v0 = xr[lane], v1 = xr[lane + 64];
    float v2 = (lane < 52) ? xr[lane + 128] : 0.f;
    float s = wave_reduce_add(v0 + v1 + v2);
    float ss = wave_reduce_add(v0 * v0 + v1 * v1 + v2 * v2);
    float mean = s * (1.f / 180.f);
    float rstd = rsqrtf(ss * (1.f / 180.f) - mean * mean + 1e-5f);
    bf16* ar = Axs + r * 200;
    ar[lane] = __float2bfloat16((v0 - mean) * rstd * gw[lane] + bw[lane]);
    ar[lane + 64] = __float2bfloat16((v1 - mean) * rstd * gw[lane + 64] + bw[lane + 64]);
    float v3 = (lane < 52) ? ((v2 - mean) * rstd * gw[lane + 128] + bw[lane + 128]) : 0.f;
    ar[lane + 128] = __float2bfloat16(v3);
  }
  __syncthreads();
  int m = lane & 15, q = lane >> 4, mh = wv & 1, ng = wv >> 1;  // ng 0..3
  int rA = mh * 16 + m;
  // FC1 + GELU -> Hs : ng covers nt [ng*12, min(ng*12+12, 46))
  for (int i = 0; i < 12; i += 2) {
    int nt0 = ng * 12 + i;
    if (nt0 >= 46) break;
    bool two = (nt0 + 1) < 46;
    float4v acc0 = {0.f, 0.f, 0.f, 0.f}, acc1 = {0.f, 0.f, 0.f, 0.f};
#pragma unroll
    for (int kb = 0; kb < 6; kb++) {
      short8v a = *(const short8v*)(Axs + rA * 200 + kb * 32 + q * 8);
      short8v b0 = ((const short8v*)B1)[(nt0 * 6 + kb) * 64 + lane];
      acc0 = __builtin_amdgcn_mfma_f32_16x16x32_bf16(a, b0, acc0, 0, 0, 0);
      if (two) {
        short8v b1 = ((const short8v*)B1)[((nt0 + 1) * 6 + kb) * 64 + lane];
        acc1 = __builtin_amdgcn_mfma_f32_16x16x32_bf16(a, b1, acc1, 0, 0, 0);
      }
    }
    int n0 = nt0 * 16 + m;
    float bb0 = b1t[n0];
    float bb1 = two ? b1t[n0 + 16] : 0.f;
#pragma unroll
    for (int reg = 0; reg < 4; reg++) {
      int r = mh * 16 + q * 4 + reg;
      Hs[r * 744 + n0] = __float2bfloat16(gelu_f(acc0[reg] + bb0));
      if (two) Hs[r * 744 + n0 + 16] = __float2bfloat16(gelu_f(acc1[reg] + bb1));
    }
  }
  __syncthreads();
  // FC2 + residual : ng covers nt [ng*3, ng*3+3)
  for (int i = 0; i < 3; i += 2) {
    int nt0 = ng * 3 + i;
    bool two = (i + 1) < 3;
    float4v acc0 = {0.f, 0.f, 0.f, 0.f}, acc1 = {0.f, 0.f, 0.f, 0.f};
    for (int kb = 0; kb < 23; kb++) {
      short8v a = *(const short8v*)(Hs + rA * 744 + kb * 32 + q * 8);
      short8v b0 = ((const short8v*)B2)[(nt0 * 23 + kb) * 64 + lane];
      acc0 = __builtin_amdgcn_mfma_f32_16x16x32_bf16(a, b0, acc0, 0, 0, 0);
      if (two) {
        short8v b1 = ((const short8v*)B2)[((nt0 + 1) * 23 + kb) * 64 + lane];
        acc1 = __builtin_amdgcn_mfma_f32_16x16x32_bf16(a, b1, acc1, 0, 0, 0);
      }
    }
    int n0 = nt0 * 16 + m, n1 = n0 + 16;
#pragma unroll
    for (int reg = 0; reg < 4; reg++) {
      long rw = row0 + mh * 16 + q * 4 + reg;
      if (n0 < 180) xio[rw * 180 + n0] += acc0[reg] + fc2b[n0];
      if (two && n1 < 180) xio[rw * 180 + n1] += acc1[reg] + fc2b[n1];
    }
  }
}

// ---------------- launch ----------------

extern "C" void kernel_launch(void* const* d_in, const int* in_sizes, int n_in,
                              void* d_out, int out_size, void* d_ws, size_t ws_size,
                              hipStream_t stream) {
  const float* x = (const float*)d_in[0];
  const float* ln1g = (const float*)d_in[1];
  const float* ln1b = (const float*)d_in[2];
  const float* qkvw = (const float*)d_in[3];
  const float* qkvbias = (const float*)d_in[4];
  const float* btab = (const float*)d_in[5];
  const float* projw = (const float*)d_in[6];
  const float* projb = (const float*)d_in[7];
  const float* cw1 = (const float*)d_in[8];
  const float* cb1 = (const float*)d_in[9];
  const float* cw2 = (const float*)d_in[10];
  const float* cb2 = (const float*)d_in[11];
  const float* caw1 = (const float*)d_in[12];
  const float* cab1 = (const float*)d_in[13];
  const float* caw2 = (const float*)d_in[14];
  const float* cab2 = (const float*)d_in[15];
  const float* ln2g = (const float*)d_in[16];
  const float* ln2b = (const float*)d_in[17];
  const float* fc1w = (const float*)d_in[18];
  const float* fc1b = (const float*)d_in[19];
  const float* fc2w = (const float*)d_in[20];
  const float* fc2b = (const float*)d_in[21];
  const int* rpi = (const int*)d_in[22];
  float* out = (float*)d_out;

  size_t off = 0;
  char* wsb = (char*)d_ws;
  auto alloc = [&](size_t bytes) -> char* {
    char* p = wsb + off;
    off = (off + bytes + 255) & ~(size_t)255;
    return p;
  };
  bf16* xnf = (bf16*)alloc((size_t)N_TOK * 192 * 2);   // also reused as attnf
  bf16* y60f = (bf16*)alloc((size_t)N_TOK * 64 * 2);
  bf16* y180f = (bf16*)alloc((size_t)N_TOK * 192 * 2);
  bf16* qkvb = (bf16*)alloc((size_t)N_TOK * 544 * 2);
  bf16* Bq = (bf16*)alloc(34 * 6 * 64 * 8 * 2);
  float* btq = (float*)alloc(544 * 4);
  bf16* Bp = (bf16*)alloc(12 * 6 * 64 * 8 * 2);
  bf16* B1 = (bf16*)alloc(46 * 6 * 64 * 8 * 2);
  float* b1t = (float*)alloc(736 * 4);
  bf16* B2 = (bf16*)alloc(12 * 23 * 64 * 8 * 2);
  bf16* Bc1 = (bf16*)alloc(9 * 6 * 4 * 64 * 8 * 2);
  bf16* Bc2 = (bf16*)alloc(9 * 2 * 12 * 64 * 8 * 2);
  float* chsum = (float*)alloc(720 * 4);
  float* a_se = (float*)alloc(720 * 4);
  if (off > ws_size) return;
  bf16* attnf = xnf;  // xnf dead after k_qkv/k_conv1; reuse for attention output

  k_zero<<<3, 256, 0, stream>>>(chsum, 720);
  k_pack_qkv_b<<<51, 256, 0, stream>>>(qkvw, Bq);
  k_pack_qkv_bias<<<3, 256, 0, stream>>>(qkvbias, btq);
  k_pack_proj_b<<<18, 256, 0, stream>>>(projw, Bp);
  k_pack_fc1_b<<<69, 256, 0, stream>>>(fc1w, B1);
  k_pack_fc1_bias<<<3, 256, 0, stream>>>(fc1b, b1t);
  k_pack_fc2_b<<<69, 256, 0, stream>>>(fc2w, B2);
  k_pack_conv1_b<<<54, 256, 0, stream>>>(cw1, Bc1);
  k_pack_conv2_b<<<54, 256, 0, stream>>>(cw2, Bc2);

  k_ln1<<<65536, 256, 0, stream>>>(x, ln1g, ln1b, xnf);
  k_conv1_mfma<<<4096, 256, 0, stream>>>(xnf, Bc1, cb1, y60f);
  k_conv2_mfma<<<4096, 256, 0, stream>>>(y60f, Bc2, cb2, y180f, chsum);
  k_se<<<4, 192, 0, stream>>>(chsum, caw1, cab1, caw2, cab2, a_se);
  k_qkv_mfma<<<4096, 256, 0, stream>>>(xnf, Bq, btq, qkvb);
  k_attn<<<dim3(4096, 6), 256, 0, stream>>>(qkvb, btab, rpi, attnf);
  k_proj_mfma<<<4096, 256, 0, stream>>>(attnf, Bp, projb, x, y180f, a_se, out);
  k_mlp_mfma<<<8192, 512, 0, stream>>>(out, ln2g, ln2b, B1, b1t, B2, fc2b);
}

// Round 6
// 1908.378 us; speedup vs baseline: 1.4069x; 1.2158x over previous
//
#include <hip/hip_runtime.h>
#include <hip/hip_bf16.h>

typedef __hip_bfloat16 bf16;
typedef __attribute__((ext_vector_type(8))) short short8v;
typedef __attribute__((ext_vector_type(4))) float float4v;

#define N_TOK (4 * 65536)
#define IMG 256

__device__ __forceinline__ float wave_reduce_add(float v) {
#pragma unroll
  for (int m = 32; m > 0; m >>= 1) v += __shfl_xor(v, m, 64);
  return v;
}

__device__ __forceinline__ float gelu_f(float v) {
  return 0.5f * v * (1.f + erff(v * 0.70710678118654752f));
}

// fragment-linear activation layout: [t=row/64][ch=k/8][r=row%64][j=k%8]
__device__ __forceinline__ size_t frag_idx(long row, int k) {
  return ((((row >> 6) * 24) + (k >> 3)) << 9) + ((long)(row & 63) << 3) + (k & 7);
}

// ---------------- small utility / pack kernels ----------------

__global__ void k_zero(float* __restrict__ p, int n) {
  int i = blockIdx.x * 256 + threadIdx.x;
  if (i < n) p[i] = 0.f;
}

// qkv B pack: [nt 36][kb 6][lane 64][8]. n-order: n = h*96 + mat*32 + d (d<30
// valid, 30..31 zero). q (mat==0) pre-scaled. 16B-aligned per-head slices.
__global__ void k_pack_qkv_b(const float* __restrict__ w, bf16* __restrict__ B) {
  int e = blockIdx.x * 256 + threadIdx.x;
  if (e >= 36 * 6 * 64) return;
  int lane = e & 63, kb = (e >> 6) % 6, nt = e / (6 * 64);
  int n = nt * 16 + (lane & 15);
  int kbase = kb * 32 + (lane >> 4) * 8;
  bf16* out = B + (size_t)e * 8;
  int hh = n / 96, rr = n % 96, mat = rr / 32, d = rr % 32;
#pragma unroll
  for (int j = 0; j < 8; j++) {
    int k = kbase + j;
    float v = 0.f;
    if (d < 30 && k < 180) {
      int o = mat * 180 + hh * 30 + d;
      float s = (mat == 0) ? 0.18257418583505537f : 1.f;
      v = w[o * 180 + k] * s;
    }
    out[j] = __float2bfloat16(v);
  }
}

__global__ void k_pack_qkv_bias(const float* __restrict__ b, float* __restrict__ bt) {
  int n = blockIdx.x * 256 + threadIdx.x;
  if (n >= 576) return;
  int hh = n / 96, rr = n % 96, mat = rr / 32, d = rr % 32;
  float v = 0.f;
  if (d < 30) {
    int o = mat * 180 + hh * 30 + d;
    float s = (mat == 0) ? 0.18257418583505537f : 1.f;
    v = b[o] * s;
  }
  bt[n] = v;
}

// attention bias pre-gather: bt6[h][mq][nk] = btab[rpi[mq*64+nk]*6 + h]
__global__ void k_pack_bias6(const float* __restrict__ btab, const int* __restrict__ rpi,
                             float* __restrict__ bt6) {
  int e = blockIdx.x * 256 + threadIdx.x;
  if (e >= 6 * 4096) return;
  int h = e >> 12, r = e & 4095;
  bt6[e] = btab[rpi[r] * 6 + h];
}

// proj B pack: [nt 12][kb 6][lane][8]: B[k][n] = proj_w[n*180+k]
__global__ void k_pack_proj_b(const float* __restrict__ w, bf16* __restrict__ B) {
  int e = blockIdx.x * 256 + threadIdx.x;
  if (e >= 12 * 6 * 64) return;
  int lane = e & 63, kb = (e >> 6) % 6, nt = e / (6 * 64);
  int n = nt * 16 + (lane & 15);
  int kbase = kb * 32 + (lane >> 4) * 8;
  bf16* out = B + (size_t)e * 8;
#pragma unroll
  for (int j = 0; j < 8; j++) {
    int k = kbase + j;
    out[j] = __float2bfloat16((n < 180 && k < 180) ? w[n * 180 + k] : 0.f);
  }
}

// fc1 B pack: [nt 46][kb 6][lane][8]: B[k][n] = fc1_w[n*180+k]
__global__ void k_pack_fc1_b(const float* __restrict__ w, bf16* __restrict__ B) {
  int e = blockIdx.x * 256 + threadIdx.x;
  if (e >= 46 * 6 * 64) return;
  int lane = e & 63, kb = (e >> 6) % 6, nt = e / (6 * 64);
  int n = nt * 16 + (lane & 15);
  int kbase = kb * 32 + (lane >> 4) * 8;
  bf16* out = B + (size_t)e * 8;
#pragma unroll
  for (int j = 0; j < 8; j++) {
    int k = kbase + j;
    out[j] = __float2bfloat16((n < 720 && k < 180) ? w[n * 180 + k] : 0.f);
  }
}

__global__ void k_pack_fc1_bias(const float* __restrict__ b, float* __restrict__ bt) {
  int n = blockIdx.x * 256 + threadIdx.x;
  if (n >= 736) return;
  bt[n] = (n < 720) ? b[n] : 0.f;
}

// fc2 B pack: [nt 12][kb 23][lane][8]: B[k][n] = fc2_w[n*720+k]
__global__ void k_pack_fc2_b(const float* __restrict__ w, bf16* __restrict__ B) {
  int e = blockIdx.x * 256 + threadIdx.x;
  if (e >= 12 * 23 * 64) return;
  int lane = e & 63, kb = (e >> 6) % 23, nt = e / (23 * 64);
  int n = nt * 16 + (lane & 15);
  int kbase = kb * 32 + (lane >> 4) * 8;
  bf16* out = B + (size_t)e * 8;
#pragma unroll
  for (int j = 0; j < 8; j++) {
    int k = kbase + j;
    out[j] = __float2bfloat16((n < 180 && k < 720) ? w[n * 720 + k] : 0.f);
  }
}

// conv1 B pack: frag = ((dy*6+kb)*3+dx)*4+nt ; B[k][n] = w1[n][k][dy][dx]
__global__ void k_pack_conv1_b(const float* __restrict__ w, bf16* __restrict__ B) {
  int e = blockIdx.x * 256 + threadIdx.x;
  if (e >= 9 * 6 * 4 * 64) return;
  int lane = e & 63;
  int t = e >> 6;
  int nt = t & 3;
  int t2 = t >> 2;
  int dx = t2 % 3;
  int t3 = t2 / 3;
  int kb = t3 % 6, dy = t3 / 6;
  int n = nt * 16 + (lane & 15);
  int kbase = kb * 32 + (lane >> 4) * 8;
  bf16* out = B + (size_t)e * 8;
#pragma unroll
  for (int j = 0; j < 8; j++) {
    int k = kbase + j;
    float v = (n < 60 && k < 180) ? w[((n * 180 + k) * 3 + dy) * 3 + dx] : 0.f;
    out[j] = __float2bfloat16(v);
  }
}

// conv2 B pack: frag = ((dy*2+kb)*3+dx)*12+nt ; B[k][n] = w2[n][k][dy][dx]
__global__ void k_pack_conv2_b(const float* __restrict__ w, bf16* __restrict__ B) {
  int e = blockIdx.x * 256 + threadIdx.x;
  if (e >= 9 * 2 * 12 * 64) return;
  int lane = e & 63;
  int t = e >> 6;
  int nt = t % 12;
  int t2 = t / 12;
  int dx = t2 % 3;
  int t3 = t2 / 3;
  int kb = t3 & 1, dy = t3 >> 1;
  int n = nt * 16 + (lane & 15);
  int kbase = kb * 32 + (lane >> 4) * 8;
  bf16* out = B + (size_t)e * 8;
#pragma unroll
  for (int j = 0; j < 8; j++) {
    int k = kbase + j;
    float v = (n < 180 && k < 60) ? w[((n * 60 + k) * 3 + dy) * 3 + dx] : 0.f;
    out[j] = __float2bfloat16(v);
  }
}

// ---------------- LN1: x -> xn (frag layout, K padded to 192 w/ zeros) ----------------

__global__ __launch_bounds__(256) void k_ln1(const float* __restrict__ x,
                                             const float* __restrict__ gw,
                                             const float* __restrict__ bw,
                                             bf16* __restrict__ xnf) {
  int wv = threadIdx.x >> 6, lane = threadIdx.x & 63;
  long row = (long)blockIdx.x * 4 + wv;
  const float* xr = x + row * 180;
  float v0 = xr[lane];
  float v1 = xr[lane + 64];
  float v2 = (lane < 52) ? xr[lane + 128] : 0.f;
  float s = wave_reduce_add(v0 + v1 + v2);
  float ss = wave_reduce_add(v0 * v0 + v1 * v1 + v2 * v2);
  float mean = s * (1.f / 180.f);
  float rstd = rsqrtf(ss * (1.f / 180.f) - mean * mean + 1e-5f);
  bf16* base = xnf + (((row >> 6) * 24) << 9) + ((long)(row & 63) << 3);
  int ch = lane >> 3, j = lane & 7;
  base[((size_t)ch << 9) + j] =
      __float2bfloat16((v0 - mean) * rstd * gw[lane] + bw[lane]);
  base[((size_t)(ch + 8) << 9) + j] =
      __float2bfloat16((v1 - mean) * rstd * gw[lane + 64] + bw[lane + 64]);
  float v3 = (lane < 52) ? ((v2 - mean) * rstd * gw[lane + 128] + bw[lane + 128]) : 0.f;
  base[((size_t)(ch + 16) << 9) + j] = __float2bfloat16(v3);
}

// ---------------- conv1 3x3 180->60 + GELU via MFMA ----------------

__global__ __launch_bounds__(256) void k_conv1_mfma(const bf16* __restrict__ xnf,
                                                    const bf16* __restrict__ Bc1,
                                                    const float* __restrict__ b1,
                                                    bf16* __restrict__ y60f) {
  __shared__ bf16 Ls[3 * 12 * 66 * 8];  // 38016 B
  int tid = threadIdx.x;
  int bid = blockIdx.x;
  int b = bid >> 10, rem = bid & 1023, iy = rem >> 2, xb = rem & 3;
  int ix0 = xb << 6;
  long ibase = (long)b * 65536;
  int lane = tid & 63, wv = tid >> 6;
  int m = lane & 15, q = lane >> 4;
  float4v acc[4];
#pragma unroll
  for (int nt = 0; nt < 4; nt++) acc[nt] = (float4v){0.f, 0.f, 0.f, 0.f};
  const short8v* Bp = (const short8v*)Bc1;
  for (int half = 0; half < 2; half++) {
    for (int idx = tid; idx < 3 * 12 * 66; idx += 256) {
      int px = idx % 66;
      int t2 = idx / 66;
      int chb = t2 % 12, r = t2 / 12;
      int iy2 = iy - 1 + r, ix = ix0 - 1 + px;
      uint4 v = make_uint4(0u, 0u, 0u, 0u);
      if (iy2 >= 0 && iy2 < IMG && ix >= 0 && ix < IMG) {
        long tok = ibase + iy2 * IMG + ix;
        v = *(const uint4*)(xnf + ((tok >> 6) * 24 + half * 12 + chb) * 512 +
                            (tok & 63) * 8);
      }
      *(uint4*)(Ls + (size_t)idx * 8) = v;
    }
    __syncthreads();
#pragma unroll
    for (int kbl = 0; kbl < 3; kbl++) {
      int kb = half * 3 + kbl;
#pragma unroll
      for (int dy = 0; dy < 3; dy++) {
        const short8v* ab =
            (const short8v*)Ls + ((dy * 12 + kbl * 4 + q) * 66 + wv * 16 + m);
#pragma unroll
        for (int dx = 0; dx < 3; dx++) {
          short8v a = ab[dx];
          const short8v* bp = Bp + (size_t)(((dy * 6 + kb) * 3 + dx) * 4) * 64 + lane;
#pragma unroll
          for (int nt = 0; nt < 4; nt++)
            acc[nt] = __builtin_amdgcn_mfma_f32_16x16x32_bf16(a, bp[nt * 64], acc[nt], 0, 0, 0);
        }
      }
    }
    __syncthreads();
  }
  bf16* outb = y60f + (size_t)bid * 4096;
#pragma unroll
  for (int nt = 0; nt < 4; nt++) {
    int n = nt * 16 + m;
    float bias = (n < 60) ? b1[n] : 0.f;
#pragma unroll
    for (int reg = 0; reg < 4; reg++) {
      int p = wv * 16 + q * 4 + reg;
      float v = (n < 60) ? gelu_f(acc[nt][reg] + bias) : 0.f;
      outb[((n >> 3) << 9) + (p << 3) + (n & 7)] = __float2bfloat16(v);
    }
  }
}

// ---------------- conv2 3x3 60->180 via MFMA + fused channel sums ----------------

__global__ __launch_bounds__(256) void k_conv2_mfma(const bf16* __restrict__ y60f,
                                                    const bf16* __restrict__ Bc2,
                                                    const float* __restrict__ b2,
                                                    bf16* __restrict__ y180f,
                                                    float* __restrict__ chsum) {
  __shared__ bf16 Ls[3 * 8 * 66 * 8];  // 25344 B
  int tid = threadIdx.x;
  int bid = blockIdx.x;
  int b = bid >> 10, rem = bid & 1023, iy = rem >> 2, xb = rem & 3;
  int ix0 = xb << 6;
  long ibase = (long)b * 65536;
  for (int idx = tid; idx < 3 * 8 * 66; idx += 256) {
    int px = idx % 66;
    int t2 = idx / 66;
    int chb = t2 % 8, r = t2 / 8;
    int iy2 = iy - 1 + r, ix = ix0 - 1 + px;
    uint4 v = make_uint4(0u, 0u, 0u, 0u);
    if (iy2 >= 0 && iy2 < IMG && ix >= 0 && ix < IMG) {
      long tok = ibase + iy2 * IMG + ix;
      v = *(const uint4*)(y60f + ((tok >> 6) * 8 + chb) * 512 + (tok & 63) * 8);
    }
    *(uint4*)(Ls + (size_t)idx * 8) = v;
  }
  __syncthreads();
  int lane = tid & 63, wv = tid >> 6;
  int m = lane & 15, q = lane >> 4;
  float4v acc[12];
#pragma unroll
  for (int nt = 0; nt < 12; nt++) acc[nt] = (float4v){0.f, 0.f, 0.f, 0.f};
  const short8v* Bp = (const short8v*)Bc2;
#pragma unroll
  for (int dy = 0; dy < 3; dy++) {
#pragma unroll
    for (int kb = 0; kb < 2; kb++) {
      const short8v* ab =
          (const short8v*)Ls + ((dy * 8 + kb * 4 + q) * 66 + wv * 16 + m);
#pragma unroll
      for (int dx = 0; dx < 3; dx++) {
        short8v a = ab[dx];
        const short8v* bp = Bp + (size_t)(((dy * 2 + kb) * 3 + dx) * 12) * 64 + lane;
#pragma unroll
        for (int nt = 0; nt < 12; nt++)
          acc[nt] = __builtin_amdgcn_mfma_f32_16x16x32_bf16(a, bp[nt * 64], acc[nt], 0, 0, 0);
      }
    }
  }
  float csum[12];
  bf16* outb = y180f + (size_t)bid * 12288;
#pragma unroll
  for (int nt = 0; nt < 12; nt++) {
    int n = nt * 16 + m;
    float bias = (n < 180) ? b2[n] : 0.f;
    float s = 0.f;
#pragma unroll
    for (int reg = 0; reg < 4; reg++) {
      float v = acc[nt][reg] + bias;
      s += v;
      int p = wv * 16 + q * 4 + reg;
      if (n < 180) outb[((n >> 3) << 9) + (p << 3) + (n & 7)] = __float2bfloat16(v);
    }
    s += __shfl_xor(s, 16, 64);
    s += __shfl_xor(s, 32, 64);
    csum[nt] = s;
  }
  __syncthreads();
  float* red = (float*)Ls;  // [4][192]
  if (q == 0) {
#pragma unroll
    for (int nt = 0; nt < 12; nt++) red[wv * 192 + nt * 16 + m] = csum[nt];
  }
  __syncthreads();
  if (tid < 180) {
    float tot = red[tid] + red[192 + tid] + red[384 + tid] + red[576 + tid];
    atomicAdd(&chsum[b * 180 + tid], tot);
  }
}

// ---------------- SE ----------------

__global__ __launch_bounds__(192) void k_se(const float* __restrict__ cs,
                                            const float* __restrict__ w1,
                                            const float* __restrict__ b1,
                                            const float* __restrict__ w2,
                                            const float* __restrict__ b2,
                                            float* __restrict__ a_se) {
  __shared__ float m[180];
  __shared__ float hid[6];
  int b = blockIdx.x, t = threadIdx.x;
  if (t < 180) m[t] = cs[b * 180 + t] * (1.f / 65536.f);
  __syncthreads();
  if (t < 6) {
    float s = b1[t];
    for (int c = 0; c < 180; c++) s += m[c] * w1[t * 180 + c];
    hid[t] = fmaxf(s, 0.f);
  }
  __syncthreads();
  if (t < 180) {
    float s = b2[t];
#pragma unroll
    for (int j = 0; j < 6; j++) s += hid[j] * w2[t * 6 + j];
    a_se[b * 180 + t] = 1.f / (1.f + __expf(-s));
  }
}

// ---------------- qkv GEMM via MFMA: 64 rows/block, N=576, K=192 ----------------

__global__ __launch_bounds__(256) void k_qkv_mfma(const bf16* __restrict__ xnf,
                                                  const bf16* __restrict__ Bq,
                                                  const float* __restrict__ btq,
                                                  bf16* __restrict__ qkvb) {
  __shared__ bf16 As[24 * 64 * 8];  // 24 KB, frag-linear
  int tid = threadIdx.x;
  const uint4* src = (const uint4*)(xnf + (size_t)blockIdx.x * 12288);
  uint4* dst = (uint4*)As;
#pragma unroll
  for (int it = 0; it < 6; it++) dst[it * 256 + tid] = src[it * 256 + tid];
  __syncthreads();
  int lane = tid & 63, wv = tid >> 6;
  int m = lane & 15, q = lane >> 4;
  long row0 = (long)blockIdx.x * 64 + wv * 16;
  const short8v* Ap = (const short8v*)As;
  const short8v* Bp = (const short8v*)Bq;
  for (int nt = 0; nt < 36; nt += 2) {
    float4v acc0 = {0.f, 0.f, 0.f, 0.f}, acc1 = {0.f, 0.f, 0.f, 0.f};
#pragma unroll
    for (int kb = 0; kb < 6; kb++) {
      short8v a = Ap[(kb * 4 + q) * 64 + wv * 16 + m];
      short8v b0 = Bp[(nt * 6 + kb) * 64 + lane];
      short8v b1 = Bp[((nt + 1) * 6 + kb) * 64 + lane];
      acc0 = __builtin_amdgcn_mfma_f32_16x16x32_bf16(a, b0, acc0, 0, 0, 0);
      acc1 = __builtin_amdgcn_mfma_f32_16x16x32_bf16(a, b1, acc1, 0, 0, 0);
    }
    int n0 = nt * 16 + m, n1 = n0 + 16;
    float bb0 = btq[n0], bb1 = btq[n1];
#pragma unroll
    for (int reg = 0; reg < 4; reg++) {
      long rw = row0 + q * 4 + reg;
      qkvb[rw * 576 + n0] = __float2bfloat16(acc0[reg] + bb0);
      qkvb[rw * 576 + n1] = __float2bfloat16(acc1[reg] + bb1);
    }
  }
}

// ---------------- attention via MFMA: 1 wave per (window, head) ----------------
// qkvb token stride 576: Q at h*96+0, K at h*96+32, V at h*96+64 (d 30..31 = 0).
// S = mfma(Q, K^T) 16x; bias from bt6; wave-parallel softmax; P->LDS(72 stride);
// O = mfma(P, V) 16x -> attnf frag layout.

__global__ __launch_bounds__(64) void k_attn(const bf16* __restrict__ qkvb,
                                             const float* __restrict__ bt6,
                                             bf16* __restrict__ attnf) {
  __shared__ bf16 P_lds[64 * 72];  // 9216 B
  int lane = threadIdx.x;
  int h = blockIdx.y;
  int bid = blockIdx.x;
  int b = bid >> 10, rem = bid & 1023, wi = rem >> 5, wj = rem & 31;
  long ibase = (long)b * 65536;
  // zero k-pad (180..191) once per token, head-0 blocks only
  if (h == 0) {
    long g = ibase + (wi * 8 + (lane >> 3)) * IMG + wj * 8 + (lane & 7);
    bf16* bp = attnf + (((g >> 6) * 24) << 9) + ((long)(g & 63) << 3);
    *(uint2*)(bp + (22 << 9) + 4) = make_uint2(0u, 0u);
    *(uint4*)(bp + (23 << 9)) = make_uint4(0u, 0u, 0u, 0u);
  }
  int ml = lane & 15, q = lane >> 4;
  // tokens for window rows {ml, 16+ml, 32+ml, 48+ml}
  long tokr[4];
#pragma unroll
  for (int mt = 0; mt < 4; mt++) {
    int t = mt * 16 + ml;
    tokr[mt] = ibase + (wi * 8 + (t >> 3)) * IMG + wj * 8 + (t & 7);
  }
  // Q A-frags (row = ml) and K B-frags (col = ml); k-slice = q*8, K=32 single block
  short8v aQ[4], bK[4];
#pragma unroll
  for (int mt = 0; mt < 4; mt++) {
    aQ[mt] = *(const short8v*)(qkvb + tokr[mt] * 576 + h * 96 + q * 8);
    bK[mt] = *(const short8v*)(qkvb + tokr[mt] * 576 + h * 96 + 32 + q * 8);
  }
  // S = Q K^T  (C: row=m_q=(q*4+reg)+mt*16, col=n_k=ml+nt*16)
  float4v s[4][4];
#pragma unroll
  for (int mt = 0; mt < 4; mt++)
#pragma unroll
    for (int nt = 0; nt < 4; nt++)
      s[mt][nt] = __builtin_amdgcn_mfma_f32_16x16x32_bf16(
          aQ[mt], bK[nt], (float4v){0.f, 0.f, 0.f, 0.f}, 0, 0, 0);
  // + bias
  const float* bh = bt6 + h * 4096;
#pragma unroll
  for (int mt = 0; mt < 4; mt++)
#pragma unroll
    for (int nt = 0; nt < 4; nt++) {
      int nk = nt * 16 + ml;
#pragma unroll
      for (int reg = 0; reg < 4; reg++)
        s[mt][nt][reg] += bh[(mt * 16 + q * 4 + reg) * 64 + nk];
    }
  // softmax over keys (4 in-reg tiles x 16-lane group)
#pragma unroll
  for (int mt = 0; mt < 4; mt++) {
#pragma unroll
    for (int reg = 0; reg < 4; reg++) {
      float mx = fmaxf(fmaxf(s[mt][0][reg], s[mt][1][reg]),
                       fmaxf(s[mt][2][reg], s[mt][3][reg]));
      mx = fmaxf(mx, __shfl_xor(mx, 1, 64));
      mx = fmaxf(mx, __shfl_xor(mx, 2, 64));
      mx = fmaxf(mx, __shfl_xor(mx, 4, 64));
      mx = fmaxf(mx, __shfl_xor(mx, 8, 64));
      float e0 = __expf(s[mt][0][reg] - mx);
      float e1 = __expf(s[mt][1][reg] - mx);
      float e2 = __expf(s[mt][2][reg] - mx);
      float e3 = __expf(s[mt][3][reg] - mx);
      float sm = e0 + e1 + e2 + e3;
      sm += __shfl_xor(sm, 1, 64);
      sm += __shfl_xor(sm, 2, 64);
      sm += __shfl_xor(sm, 4, 64);
      sm += __shfl_xor(sm, 8, 64);
      float inv = 1.f / sm;
      s[mt][0][reg] = e0 * inv;
      s[mt][1][reg] = e1 * inv;
      s[mt][2][reg] = e2 * inv;
      s[mt][3][reg] = e3 * inv;
    }
  }
  // P -> LDS (bf16, row stride 72)
#pragma unroll
  for (int mt = 0; mt < 4; mt++)
#pragma unroll
    for (int reg = 0; reg < 4; reg++) {
      int mq = mt * 16 + q * 4 + reg;
#pragma unroll
      for (int nt = 0; nt < 4; nt++)
        P_lds[mq * 72 + nt * 16 + ml] = __float2bfloat16(s[mt][nt][reg]);
    }
  __syncthreads();
  // O = P V : A = P (M=q rows, K=keys), B = V (K=keys, N=32 d-pad)
  float4v o[4][2];
#pragma unroll
  for (int mt = 0; mt < 4; mt++)
#pragma unroll
    for (int nt = 0; nt < 2; nt++) o[mt][nt] = (float4v){0.f, 0.f, 0.f, 0.f};
#pragma unroll
  for (int kb = 0; kb < 2; kb++) {
    int krow = kb * 4 + q;  // window row of keys kb*32+q*8 .. +7
    long tokb = ibase + (wi * 8 + krow) * IMG + wj * 8;
    short8v bV[2];
#pragma unroll
    for (int nt = 0; nt < 2; nt++) {
      int d = nt * 16 + ml;  // 30,31 read packed zeros
      short8v v;
#pragma unroll
      for (int j = 0; j < 8; j++)
        v[j] = ((const short*)qkvb)[(tokb + j) * 576 + h * 96 + 64 + d];
      bV[nt] = v;
    }
#pragma unroll
    for (int mt = 0; mt < 4; mt++) {
      short8v aP = *(const short8v*)(P_lds + (mt * 16 + ml) * 72 + kb * 32 + q * 8);
#pragma unroll
      for (int nt = 0; nt < 2; nt++)
        o[mt][nt] = __builtin_amdgcn_mfma_f32_16x16x32_bf16(aP, bV[nt], o[mt][nt], 0, 0, 0);
    }
  }
  // store O -> attnf frag layout
#pragma unroll
  for (int mt = 0; mt < 4; mt++)
#pragma unroll
    for (int nt = 0; nt < 2; nt++) {
      int d = nt * 16 + ml;
      if (d < 30) {
#pragma unroll
        for (int reg = 0; reg < 4; reg++) {
          int mq = mt * 16 + q * 4 + reg;
          long g = ibase + (wi * 8 + (mq >> 3)) * IMG + wj * 8 + (mq & 7);
          attnf[frag_idx(g, h * 30 + d)] = __float2bfloat16(o[mt][nt][reg]);
        }
      }
    }
}

// ---------------- proj via MFMA + residual combine -> out (fp32) ----------------

__global__ __launch_bounds__(256) void k_proj_mfma(const bf16* __restrict__ attnf,
                                                   const bf16* __restrict__ Bp_,
                                                   const float* __restrict__ pb,
                                                   const float* __restrict__ x0,
                                                   const bf16* __restrict__ y180f,
                                                   const float* __restrict__ a_se,
                                                   float* __restrict__ out) {
  __shared__ bf16 As[24 * 64 * 8];
  int tid = threadIdx.x;
  const uint4* src = (const uint4*)(attnf + (size_t)blockIdx.x * 12288);
  uint4* dst = (uint4*)As;
#pragma unroll
  for (int it = 0; it < 6; it++) dst[it * 256 + tid] = src[it * 256 + tid];
  __syncthreads();
  int lane = tid & 63, wv = tid >> 6;
  int m = lane & 15, q = lane >> 4;
  long row0 = (long)blockIdx.x * 64 + wv * 16;
  const short8v* Ap = (const short8v*)As;
  const short8v* Bpp = (const short8v*)Bp_;
  for (int nt = 0; nt < 12; nt += 2) {
    float4v acc0 = {0.f, 0.f, 0.f, 0.f}, acc1 = {0.f, 0.f, 0.f, 0.f};
#pragma unroll
    for (int kb = 0; kb < 6; kb++) {
      short8v a = Ap[(kb * 4 + q) * 64 + wv * 16 + m];
      short8v b0 = Bpp[(nt * 6 + kb) * 64 + lane];
      short8v b1 = Bpp[((nt + 1) * 6 + kb) * 64 + lane];
      acc0 = __builtin_amdgcn_mfma_f32_16x16x32_bf16(a, b0, acc0, 0, 0, 0);
      acc1 = __builtin_amdgcn_mfma_f32_16x16x32_bf16(a, b1, acc1, 0, 0, 0);
    }
    int n0 = nt * 16 + m, n1 = n0 + 16;
    float pb0 = pb[n0];
    float pb1 = (n1 < 180) ? pb[n1] : 0.f;
#pragma unroll
    for (int reg = 0; reg < 4; reg++) {
      long rw = row0 + q * 4 + reg;
      int bidx = (int)(rw >> 16);
      long gi0 = rw * 180 + n0;
      out[gi0] = x0[gi0] + acc0[reg] + pb0 +
                 __bfloat162float(y180f[frag_idx(rw, n0)]) * a_se[bidx * 180 + n0] * 0.01f;
      if (n1 < 180) {
        long gi1 = rw * 180 + n1;
        out[gi1] = x0[gi1] + acc1[reg] + pb1 +
                   __bfloat162float(y180f[frag_idx(rw, n1)]) * a_se[bidx * 180 + n1] * 0.01f;
      }
    }
  }
}

// ---------------- fused LN2 + FC1(GELU) + FC2 + residual, all MFMA ----------------
// 512 threads / 8 waves, 32 rows per block.

__global__ __launch_bounds__(512, 4) void k_mlp_mfma(float* __restrict__ xio,
                                                     const float* __restrict__ gw,
                                                     const float* __restrict__ bw,
                                                     const bf16* __restrict__ B1,
                                                     const float* __restrict__ b1t,
                                                     const bf16* __restrict__ B2,
                                                     const float* __restrict__ fc2b) {
  __shared__ bf16 Axs[32 * 200];  // LN'd rows, row-major, stride 200
  __shared__ bf16 Hs[32 * 744];   // hidden, row-major, stride 744
  int tid = threadIdx.x, lane = tid & 63, wv = tid >> 6;  // wv 0..7
  long row0 = (long)blockIdx.x * 32;
#pragma unroll
  for (int rr = 0; rr < 4; rr++) {
    int r = wv * 4 + rr;
    const float* xr = xio + (row0 + r) * 180;
    float v0 = xr[lane], v1 = xr[lane + 64];
    float v2 = (lane < 52) ? xr[lane + 128] : 0.f;
    float s = wave_reduce_add(v0 + v1 + v2);
    float ss = wave_reduce_add(v0 * v0 + v1 * v1 + v2 * v2);
    float mean = s * (1.f / 180.f);
    float rstd = rsqrtf(ss * (1.f / 180.f) - mean * mean + 1e-5f);
    bf16* ar = Axs + r * 200;
    ar[lane] = __float2bfloat16((v0 - mean) * rstd * gw[lane] + bw[lane]);
    ar[lane + 64] = __float2bfloat16((v1 - mean) * rstd * gw[lane + 64] + bw[lane + 64]);
    float v3 = (lane < 52) ? ((v2 - mean) * rstd * gw[lane + 128] + bw[lane + 128]) : 0.f;
    ar[lane + 128] = __float2bfloat16(v3);
  }
  __syncthreads();
  int m = lane & 15, q = lane >> 4, mh = wv & 1, ng = wv >> 1;  // ng 0..3
  int rA = mh * 16 + m;
  // FC1 + GELU -> Hs : ng covers nt [ng*12, min(ng*12+12, 46))
  for (int i = 0; i < 12; i += 2) {
    int nt0 = ng * 12 + i;
    if (nt0 >= 46) break;
    bool two = (nt0 + 1) < 46;
    float4v acc0 = {0.f, 0.f, 0.f, 0.f}, acc1 = {0.f, 0.f, 0.f, 0.f};
#pragma unroll
    for (int kb = 0; kb < 6; kb++) {
      short8v a = *(const short8v*)(Axs + rA * 200 + kb * 32 + q * 8);
      short8v b0 = ((const short8v*)B1)[(nt0 * 6 + kb) * 64 + lane];
      acc0 = __builtin_amdgcn_mfma_f32_16x16x32_bf16(a, b0, acc0, 0, 0, 0);
      if (two) {
        short8v b1 = ((const short8v*)B1)[((nt0 + 1) * 6 + kb) * 64 + lane];
        acc1 = __builtin_amdgcn_mfma_f32_16x16x32_bf16(a, b1, acc1, 0, 0, 0);
      }
    }
    int n0 = nt0 * 16 + m;
    float bb0 = b1t[n0];
    float bb1 = two ? b1t[n0 + 16] : 0.f;
#pragma unroll
    for (int reg = 0; reg < 4; reg++) {
      int r = mh * 16 + q * 4 + reg;
      Hs[r * 744 + n0] = __float2bfloat16(gelu_f(acc0[reg] + bb0));
      if (two) Hs[r * 744 + n0 + 16] = __float2bfloat16(gelu_f(acc1[reg] + bb1));
    }
  }
  __syncthreads();
  // FC2 + residual : ng covers nt [ng*3, ng*3+3)
  for (int i = 0; i < 3; i += 2) {
    int nt0 = ng * 3 + i;
    bool two = (i + 1) < 3;
    float4v acc0 = {0.f, 0.f, 0.f, 0.f}, acc1 = {0.f, 0.f, 0.f, 0.f};
    for (int kb = 0; kb < 23; kb++) {
      short8v a = *(const short8v*)(Hs + rA * 744 + kb * 32 + q * 8);
      short8v b0 = ((const short8v*)B2)[(nt0 * 23 + kb) * 64 + lane];
      acc0 = __builtin_amdgcn_mfma_f32_16x16x32_bf16(a, b0, acc0, 0, 0, 0);
      if (two) {
        short8v b1 = ((const short8v*)B2)[((nt0 + 1) * 23 + kb) * 64 + lane];
        acc1 = __builtin_amdgcn_mfma_f32_16x16x32_bf16(a, b1, acc1, 0, 0, 0);
      }
    }
    int n0 = nt0 * 16 + m, n1 = n0 + 16;
#pragma unroll
    for (int reg = 0; reg < 4; reg++) {
      long rw = row0 + mh * 16 + q * 4 + reg;
      if (n0 < 180) xio[rw * 180 + n0] += acc0[reg] + fc2b[n0];
      if (two && n1 < 180) xio[rw * 180 + n1] += acc1[reg] + fc2b[n1];
    }
  }
}

// ---------------- launch ----------------

extern "C" void kernel_launch(void* const* d_in, const int* in_sizes, int n_in,
                              void* d_out, int out_size, void* d_ws, size_t ws_size,
                              hipStream_t stream) {
  const float* x = (const float*)d_in[0];
  const float* ln1g = (const float*)d_in[1];
  const float* ln1b = (const float*)d_in[2];
  const float* qkvw = (const float*)d_in[3];
  const float* qkvbias = (const float*)d_in[4];
  const float* btab = (const float*)d_in[5];
  const float* projw = (const float*)d_in[6];
  const float* projb = (const float*)d_in[7];
  const float* cw1 = (const float*)d_in[8];
  const float* cb1 = (const float*)d_in[9];
  const float* cw2 = (const float*)d_in[10];
  const float* cb2 = (const float*)d_in[11];
  const float* caw1 = (const float*)d_in[12];
  const float* cab1 = (const float*)d_in[13];
  const float* caw2 = (const float*)d_in[14];
  const float* cab2 = (const float*)d_in[15];
  const float* ln2g = (const float*)d_in[16];
  const float* ln2b = (const float*)d_in[17];
  const float* fc1w = (const float*)d_in[18];
  const float* fc1b = (const float*)d_in[19];
  const float* fc2w = (const float*)d_in[20];
  const float* fc2b = (const float*)d_in[21];
  const int* rpi = (const int*)d_in[22];
  float* out = (float*)d_out;

  size_t off = 0;
  char* wsb = (char*)d_ws;
  auto alloc = [&](size_t bytes) -> char* {
    char* p = wsb + off;
    off = (off + bytes + 255) & ~(size_t)255;
    return p;
  };
  bf16* xnf = (bf16*)alloc((size_t)N_TOK * 192 * 2);   // also reused as attnf
  bf16* y60f = (bf16*)alloc((size_t)N_TOK * 64 * 2);
  bf16* y180f = (bf16*)alloc((size_t)N_TOK * 192 * 2);
  bf16* qkvb = (bf16*)alloc((size_t)N_TOK * 576 * 2);
  bf16* Bq = (bf16*)alloc(36 * 6 * 64 * 8 * 2);
  float* btq = (float*)alloc(576 * 4);
  bf16* Bp = (bf16*)alloc(12 * 6 * 64 * 8 * 2);
  bf16* B1 = (bf16*)alloc(46 * 6 * 64 * 8 * 2);
  float* b1t = (float*)alloc(736 * 4);
  bf16* B2 = (bf16*)alloc(12 * 23 * 64 * 8 * 2);
  bf16* Bc1 = (bf16*)alloc(9 * 6 * 4 * 64 * 8 * 2);
  bf16* Bc2 = (bf16*)alloc(9 * 2 * 12 * 64 * 8 * 2);
  float* bt6 = (float*)alloc(6 * 4096 * 4);
  float* chsum = (float*)alloc(720 * 4);
  float* a_se = (float*)alloc(720 * 4);
  if (off > ws_size) return;
  bf16* attnf = xnf;  // xnf dead after k_qkv/k_conv1; reuse for attention output

  k_zero<<<3, 256, 0, stream>>>(chsum, 720);
  k_pack_qkv_b<<<54, 256, 0, stream>>>(qkvw, Bq);
  k_pack_qkv_bias<<<3, 256, 0, stream>>>(qkvbias, btq);
  k_pack_bias6<<<96, 256, 0, stream>>>(btab, rpi, bt6);
  k_pack_proj_b<<<18, 256, 0, stream>>>(projw, Bp);
  k_pack_fc1_b<<<69, 256, 0, stream>>>(fc1w, B1);
  k_pack_fc1_bias<<<3, 256, 0, stream>>>(fc1b, b1t);
  k_pack_fc2_b<<<69, 256, 0, stream>>>(fc2w, B2);
  k_pack_conv1_b<<<54, 256, 0, stream>>>(cw1, Bc1);
  k_pack_conv2_b<<<54, 256, 0, stream>>>(cw2, Bc2);

  k_ln1<<<65536, 256, 0, stream>>>(x, ln1g, ln1b, xnf);
  k_conv1_mfma<<<4096, 256, 0, stream>>>(xnf, Bc1, cb1, y60f);
  k_conv2_mfma<<<4096, 256, 0, stream>>>(y60f, Bc2, cb2, y180f, chsum);
  k_se<<<4, 192, 0, stream>>>(chsum, caw1, cab1, caw2, cab2, a_se);
  k_qkv_mfma<<<4096, 256, 0, stream>>>(xnf, Bq, btq, qkvb);
  k_attn<<<dim3(4096, 6), 64, 0, stream>>>(qkvb, bt6, attnf);
  k_proj_mfma<<<4096, 256, 0, stream>>>(attnf, Bp, projb, x, y180f, a_se, out);
  k_mlp_mfma<<<8192, 512, 0, stream>>>(out, ln2g, ln2b, B1, b1t, B2, fc2b);
}